// Round 10
// baseline (793.534 us; speedup 1.0000x reference)
//
#include <hip/hip_runtime.h>

#define B_ 64
#define S_ 512
#define D_ 256
#define H_ 128
#define M_ 64
#define N_ (B_ * S_)                 // 32768 nodes
#define YSZ ((size_t)N_ * H_)        // 4194304 floats
#define ADJSZ ((size_t)B_ * S_ * S_) // 16777216 floats

typedef __attribute__((ext_vector_type(8))) _Float16 f16x8;
typedef __attribute__((ext_vector_type(2))) _Float16 h2;
typedef __attribute__((ext_vector_type(4))) float f32x4;

#define MFMAH(a, b, c) __builtin_amdgcn_mfma_f32_16x16x32_f16(a, b, c, 0, 0, 0)

// weight frag store: 8 n-tiles x 14 k-chunks, 64 lanes x 16B each (f16)
#define WFRAGS (8 * 14)
#define WBYTES ((size_t)WFRAGS * 64 * 16)  // 114688

__device__ __forceinline__ float fast_tanh(float x) {
  float cx = __builtin_amdgcn_fmed3f(x, -10.0f, 10.0f);
  float e = __builtin_amdgcn_exp2f(cx * 2.8853900817779268f);
  float r = __builtin_amdgcn_rcpf(e + 1.0f);
  return fmaf(-2.0f, r, 1.0f);
}
__device__ __forceinline__ float fast_sigmoid(float x) {
  float cx = __builtin_amdgcn_fmed3f(x, -30.0f, 30.0f);
  float e = __builtin_amdgcn_exp2f(cx * -1.4426950408889634f);
  return __builtin_amdgcn_rcpf(1.0f + e);
}

// element index in a [rows][Kc] f16 array, XOR-swizzled 16B (8-elem) granules
__device__ __forceinline__ int sw(int row, int col, int Kc) {
  return row * Kc + ((((col >> 3) ^ (row & 7)) << 3) | (col & 7));
}
// granule-index form for [16][128] state arrays (g = 8-elem granule 0..15)
__device__ __forceinline__ int swu(int row, int g) {
  return row * 128 + (((g ^ (row & 7)) << 3));
}

__device__ __forceinline__ f16x8 pack8(float4 a, float4 b) {
  f16x8 r;
  r[0] = (_Float16)a.x; r[1] = (_Float16)a.y;
  r[2] = (_Float16)a.z; r[3] = (_Float16)a.w;
  r[4] = (_Float16)b.x; r[5] = (_Float16)b.y;
  r[6] = (_Float16)b.z; r[7] = (_Float16)b.w;
  return r;
}

// ---------------- K0: pack f16 weight fragments (native MFMA B-frag order)
__global__ __launch_bounds__(256) void k0_prep(
    const float* __restrict__ eWih0, const float* __restrict__ eWhh0,
    const float* __restrict__ eWih1, const float* __restrict__ eWhh1,
    unsigned short* __restrict__ Wf) {
  int t = blockIdx.x * 256 + threadIdx.x;
  if (t >= WFRAGS * 64) return;
  int fid = t >> 6, lane = t & 63;
  int ntg = fid / 14, kc = fid % 14;
  int j = ntg * 16 + (lane & 15);
  int kbase = (kc < 6 ? kc : kc - 6) * 32 + (lane >> 4) * 8;
  unsigned pk[4];
#pragma unroll
  for (int ii = 0; ii < 4; ++ii) {
    unsigned p2 = 0;
#pragma unroll
    for (int s = 0; s < 2; ++s) {
      int k = kbase + ii * 2 + s;
      float wv;
      if (kc < 6)
        wv = (k < 64) ? eWih0[j * 64 + k] : eWhh0[j * 128 + (k - 64)];
      else
        wv = (k < 128) ? eWih1[j * 128 + k] : eWhh1[j * 128 + (k - 128)];
      _Float16 h = (_Float16)wv;
      unsigned short us = *(unsigned short*)&h;
      p2 |= ((unsigned)us) << (16 * s);
    }
    pk[ii] = p2;
  }
  ((uint4*)Wf)[fid * 64 + lane] = make_uint4(pk[0], pk[1], pk[2], pk[3]);
}

// ------------------------------------------- K1: P0 = x @ Wih0^T + (bih0+bhh0)
__global__ __launch_bounds__(256) void k1_gemm(
    const float* __restrict__ x, const float* __restrict__ W,
    const float* __restrict__ bih, const float* __restrict__ bhh,
    float* __restrict__ P0) {
  __shared__ float Xs[32][132];
  __shared__ float Ws[32][132];
  const int t = threadIdx.x;
  const int ty = t >> 4, tx = t & 15;
  const int n0 = blockIdx.x * 128;
  float acc[8][8];
#pragma unroll
  for (int i = 0; i < 8; ++i)
#pragma unroll
    for (int j = 0; j < 8; ++j) acc[i][j] = 0.f;

  for (int kc = 0; kc < 256; kc += 32) {
    __syncthreads();
#pragma unroll
    for (int l = 0; l < 4; ++l) {
      int idx = t + l * 256;
      int r = idx >> 3, f4 = idx & 7;
      float4 v = *(const float4*)&x[(size_t)(n0 + r) * 256 + kc + f4 * 4];
      Xs[f4 * 4 + 0][r] = v.x; Xs[f4 * 4 + 1][r] = v.y;
      Xs[f4 * 4 + 2][r] = v.z; Xs[f4 * 4 + 3][r] = v.w;
      float4 wv = *(const float4*)&W[(size_t)r * 256 + kc + f4 * 4];
      Ws[f4 * 4 + 0][r] = wv.x; Ws[f4 * 4 + 1][r] = wv.y;
      Ws[f4 * 4 + 2][r] = wv.z; Ws[f4 * 4 + 3][r] = wv.w;
    }
    __syncthreads();
#pragma unroll
    for (int kk = 0; kk < 32; ++kk) {
      float4 xa = *(const float4*)&Xs[kk][ty * 8];
      float4 xb = *(const float4*)&Xs[kk][ty * 8 + 4];
      float4 wa = *(const float4*)&Ws[kk][tx * 8];
      float4 wb = *(const float4*)&Ws[kk][tx * 8 + 4];
      float xr[8] = {xa.x, xa.y, xa.z, xa.w, xb.x, xb.y, xb.z, xb.w};
      float wr[8] = {wa.x, wa.y, wa.z, wa.w, wb.x, wb.y, wb.z, wb.w};
#pragma unroll
      for (int i = 0; i < 8; ++i)
#pragma unroll
        for (int j = 0; j < 8; ++j) acc[i][j] += xr[i] * wr[j];
    }
  }
  float bias[8];
#pragma unroll
  for (int j = 0; j < 8; ++j) bias[j] = bih[tx * 8 + j] + bhh[tx * 8 + j];
#pragma unroll
  for (int i = 0; i < 8; ++i) {
    float4 s0 = make_float4(acc[i][0] + bias[0], acc[i][1] + bias[1],
                            acc[i][2] + bias[2], acc[i][3] + bias[3]);
    float4 s1 = make_float4(acc[i][4] + bias[4], acc[i][5] + bias[5],
                            acc[i][6] + bias[6], acc[i][7] + bias[7]);
    size_t base = (size_t)(n0 + ty * 8 + i) * 128 + tx * 8;
    *(float4*)&P0[base] = s0;
    *(float4*)&P0[base + 4] = s1;
  }
}

// ------------------------- K2 v8: batched-MFMA graph RNN, 8 waves (512 thr).
// Waves 0-3 = layer0, 4-7 = layer1 (pipelined). v8: dependent MFMA chains
// split across 2/4 accumulators (chain depth 8 -> 2) + all state ds_reads
// issued up front; latency-bound step shortens.
#define K2STEP(S, PP)                                                         \
  {                                                                           \
    if (isL0 && (S) < 512) {                                                  \
      const int rd0 = ((S)&1) ^ 1;                                            \
      f16x8 bf0 = *(const f16x8*)&h0s[rd0][swu(colB, q)];                     \
      f16x8 bf1 = *(const f16x8*)&h0s[rd0][swu(colB, 4 + q)];                 \
      f16x8 bf2 = *(const f16x8*)&h0s[rd0][swu(colB, 8 + q)];                 \
      f16x8 bf3 = *(const f16x8*)&h0s[rd0][swu(colB, 12 + q)];                \
      f32x4 aA[2], aB[2];                                                     \
      _Pragma("unroll") for (int i = 0; i < 2; ++i) {                         \
        aA[i] = __builtin_bit_cast(f32x4, PP[i]);                             \
        aB[i] = (f32x4){0.f, 0.f, 0.f, 0.f};                                  \
        aA[i] = MFMAH(WA[i][0], bf0, aA[i]);                                  \
        aB[i] = MFMAH(WA[i][1], bf1, aB[i]);                                  \
        aA[i] = MFMAH(WA[i][2], bf2, aA[i]);                                  \
        aB[i] = MFMAH(WA[i][3], bf3, aB[i]);                                  \
      }                                                                       \
      int tn = ((S) + 2 < 512) ? (S) + 2 : 511;                               \
      _Pragma("unroll") for (int i = 0; i < 2; ++i)                           \
          PP[i] = *(const float4*)(p0base[i] + (size_t)tn * 128);             \
      _Pragma("unroll") for (int i = 0; i < 2; ++i) {                         \
        f32x4 acc = aA[i] + aB[i];                                            \
        float v0 = fast_tanh(acc[0]), v1 = fast_tanh(acc[1]);                 \
        float v2 = fast_tanh(acc[2]), v3 = fast_tanh(acc[3]);                 \
        int nb = (wl * 2 + i) * 16 + q * 4;                                   \
        int g = nb >> 3;                                                      \
        int idx = colB * 128 + (((g ^ (colB & 7)) << 3) | (nb & 7));          \
        h2 lo = {(_Float16)v0, (_Float16)v1};                                 \
        h2 hi = {(_Float16)v2, (_Float16)v3};                                 \
        uint2 u = {__builtin_bit_cast(unsigned, lo),                          \
                   __builtin_bit_cast(unsigned, hi)};                         \
        *(uint2*)&h0s[(S)&1][idx] = u;                                        \
      }                                                                       \
    } else if (!isL0 && (S) >= 1) {                                           \
      const int t = (S)-1;                                                    \
      const int rb = t & 1;                                                   \
      f16x8 c0 = *(const f16x8*)&h0s[rb][swu(colB, q)];                       \
      f16x8 c1 = *(const f16x8*)&h0s[rb][swu(colB, 4 + q)];                   \
      f16x8 c2 = *(const f16x8*)&h0s[rb][swu(colB, 8 + q)];                   \
      f16x8 c3 = *(const f16x8*)&h0s[rb][swu(colB, 12 + q)];                  \
      f16x8 d0 = *(const f16x8*)&h1s[rb ^ 1][swu(colB, q)];                   \
      f16x8 d1 = *(const f16x8*)&h1s[rb ^ 1][swu(colB, 4 + q)];               \
      f16x8 d2 = *(const f16x8*)&h1s[rb ^ 1][swu(colB, 8 + q)];               \
      f16x8 d3 = *(const f16x8*)&h1s[rb ^ 1][swu(colB, 12 + q)];              \
      f32x4 aA[2], aB[2], aC[2], aD[2];                                       \
      _Pragma("unroll") for (int i = 0; i < 2; ++i) {                         \
        aA[i] = b1v[i];                                                       \
        aB[i] = (f32x4){0.f, 0.f, 0.f, 0.f};                                  \
        aC[i] = aB[i];                                                        \
        aD[i] = aB[i];                                                        \
        aA[i] = MFMAH(WA[i][0], c0, aA[i]);                                   \
        aB[i] = MFMAH(WA[i][1], c1, aB[i]);                                   \
        aC[i] = MFMAH(WA[i][2], c2, aC[i]);                                   \
        aD[i] = MFMAH(WA[i][3], c3, aD[i]);                                   \
        aA[i] = MFMAH(WB[i][0], d0, aA[i]);                                   \
        aB[i] = MFMAH(WB[i][1], d1, aB[i]);                                   \
        aC[i] = MFMAH(WB[i][2], d2, aC[i]);                                   \
        aD[i] = MFMAH(WB[i][3], d3, aD[i]);                                   \
      }                                                                       \
      float m = mk[colB][t];                                                  \
      _Pragma("unroll") for (int i = 0; i < 2; ++i) {                         \
        f32x4 acc = (aA[i] + aB[i]) + (aC[i] + aD[i]);                        \
        float v0 = fast_tanh(acc[0]), v1 = fast_tanh(acc[1]);                 \
        float v2 = fast_tanh(acc[2]), v3 = fast_tanh(acc[3]);                 \
        int nb = (wl * 2 + i) * 16 + q * 4;                                   \
        int g = nb >> 3;                                                      \
        int idx = colB * 128 + (((g ^ (colB & 7)) << 3) | (nb & 7));          \
        h2 lo = {(_Float16)v0, (_Float16)v1};                                 \
        h2 hi = {(_Float16)v2, (_Float16)v3};                                 \
        uint2 u = {__builtin_bit_cast(unsigned, lo),                          \
                   __builtin_bit_cast(unsigned, hi)};                         \
        *(uint2*)&h1s[rb][idx] = u;                                           \
        float4 yv = {v0 * m, v1 * m, v2 * m, v3 * m};                         \
        *(float4*)&Y[((size_t)(b0 + colB) * 512 + t) * 128 + nb] = yv;        \
      }                                                                       \
    }                                                                         \
    __syncthreads();                                                          \
  }

__global__ __launch_bounds__(512, 1) void k2_v8(
    const float* __restrict__ P0, const float* __restrict__ Whh0,
    const float* __restrict__ Wih1, const float* __restrict__ Whh1,
    const float* __restrict__ bih1, const float* __restrict__ bhh1,
    const int* __restrict__ mask, float* __restrict__ Y) {
  __shared__ _Float16 h0s[2][16 * 128];
  __shared__ _Float16 h1s[2][16 * 128];
  __shared__ float mk[16][516];  // padded stride
  const int tid = threadIdx.x;
  const int w = tid >> 6, l = tid & 63;
  const int b0 = blockIdx.x * 16;
  const int colB = l & 15;
  const int q = l >> 4;
  const bool isL0 = (w < 4);
  const int wl = isL0 ? w : (w - 4);

  for (int i = tid; i < 16 * 512; i += 512) {
    int bb = i >> 9, t = i & 511;
    mk[bb][t] = (float)mask[(b0 + bb) * 512 + t];
  }
  for (int i = tid; i < 1024; i += 512) {
    ((unsigned*)&h0s[1][0])[i] = 0u;
    ((unsigned*)&h1s[1][0])[i] = 0u;
  }

  f16x8 WA[2][4];  // L0: Whh0 ; L1: Wih1
  f16x8 WB[2][4];  // L1 only: Whh1
  {
    const float* src = isL0 ? Whh0 : Wih1;
#pragma unroll
    for (int i = 0; i < 2; ++i)
#pragma unroll
      for (int kc = 0; kc < 4; ++kc) {
        const float* r =
            src + ((wl * 2 + i) * 16 + colB) * 128 + kc * 32 + q * 8;
        WA[i][kc] = pack8(*(const float4*)r, *(const float4*)(r + 4));
      }
    if (!isL0) {
#pragma unroll
      for (int i = 0; i < 2; ++i)
#pragma unroll
        for (int kc = 0; kc < 4; ++kc) {
          const float* r =
              Whh1 + ((wl * 2 + i) * 16 + colB) * 128 + kc * 32 + q * 8;
          WB[i][kc] = pack8(*(const float4*)r, *(const float4*)(r + 4));
        }
    }
  }
  f32x4 b1v[2];
  const float* p0base[2];
#pragma unroll
  for (int i = 0; i < 2; ++i) {
    int nb = (wl * 2 + i) * 16 + q * 4;
    if (!isL0) {
      b1v[i] = (f32x4){bih1[nb] + bhh1[nb], bih1[nb + 1] + bhh1[nb + 1],
                       bih1[nb + 2] + bhh1[nb + 2], bih1[nb + 3] + bhh1[nb + 3]};
    } else {
      b1v[i] = (f32x4){0.f, 0.f, 0.f, 0.f};
    }
    p0base[i] = P0 + (size_t)(b0 + colB) * 512 * 128 + nb;
  }
  float4 pp0[2], pp1[2];
  if (isL0) {
#pragma unroll
    for (int i = 0; i < 2; ++i) {
      pp0[i] = *(const float4*)(p0base[i]);
      pp1[i] = *(const float4*)(p0base[i] + 128);
    }
  }
  __syncthreads();

  for (int s2 = 0; s2 < 512; s2 += 2) {
    K2STEP(s2, pp0);
    K2STEP(s2 + 1, pp1);
  }
  K2STEP(512, pp0);  // epilogue: L1 computes t=511
}

// ------------------------- K3 v8: edge RNN, f16 MFMA, 8 waves, 2m x 2n/wave.
// vs v7: (a) exact sparsity skip — A cols >= step are zero, so Aq kc=0 chunk
// skipped at step 0 and kc=1 chunk skipped while step<=32; (b) per-lane
// bias/clsW constants packed f16 (register trim, targets 2 blocks/CU).
#define LDSA 0       // A      [64][64]  f16        :  8192 B
#define LDSN0 8192   // n0     2 x [64][128] f16    : 32768 B
#define LDSN1 40960  // n1     2 x [64][128] f16    : 32768 B
#define LDSPS 73728  // psum   [4][64] f32          :  1024 B
#define LDSTOT 75776

__global__ __launch_bounds__(512, 2) void k3_edge_f16(
    const float* __restrict__ Y, const unsigned short* __restrict__ Wf,
    const float* __restrict__ bih0, const float* __restrict__ bhh0,
    const float* __restrict__ bih1, const float* __restrict__ bhh1,
    const float* __restrict__ clsW, const float* __restrict__ clsb,
    float* __restrict__ adj) {
  extern __shared__ char sm[];
  _Float16* Aq = (_Float16*)(sm + LDSA);
  _Float16* N0 = (_Float16*)(sm + LDSN0);
  _Float16* N1 = (_Float16*)(sm + LDSN1);
  float* psum = (float*)(sm + LDSPS);

  const int tid = threadIdx.x;
  const int w = tid >> 6, l = tid & 63;
  const int mg = w & 1, ng = w >> 1;
  const int colL = l & 15, q = l >> 4;
  const int node0 = blockIdx.x * 64;

  for (int i = tid; i < 2048; i += 512) ((unsigned*)(sm + LDSA))[i] = 0u;
  for (int i = tid; i < 8192; i += 512) ((unsigned*)(sm + LDSN1))[i] = 0u;
  for (int i = tid; i < 8192; i += 512) {
    int nn = i >> 7, k = i & 127;
    float v = Y[(size_t)(node0 + nn) * 128 + k];
    N0[sw(nn, k, 128)] = (_Float16)v;
  }

  f16x8 Wr[2][14];
#pragma unroll
  for (int nt = 0; nt < 2; ++nt)
#pragma unroll
    for (int kc = 0; kc < 14; ++kc)
      Wr[nt][kc] =
          ((const f16x8*)Wf)[(size_t)(((2 * ng + nt) * 14) + kc) * 64 + l];

  // per-lane constants packed f16 (reg trim)
  h2 b0p, b1p, cwp;
  {
    int cg0 = (2 * ng) * 16 + colL, cg1 = (2 * ng + 1) * 16 + colL;
    b0p.x = (_Float16)(bih0[cg0] + bhh0[cg0]);
    b0p.y = (_Float16)(bih0[cg1] + bhh0[cg1]);
    b1p.x = (_Float16)(bih1[cg0] + bhh1[cg0]);
    b1p.y = (_Float16)(bih1[cg1] + bhh1[cg1]);
    cwp.x = (_Float16)clsW[cg0];
    cwp.y = (_Float16)clsW[cg1];
  }
  const float cbias = clsb[0];
  const int mval = min((node0 & 511) + l, 64);

  __syncthreads();

  int p = 0;
  for (int step = 0; step < 64; ++step) {
    _Float16* n0rd = N0 + p * 8192;
    _Float16* n0wr = N0 + (p ^ 1) * 8192;
    _Float16* n1rd = N1 + p * 8192;
    _Float16* n1wr = N1 + (p ^ 1) * 8192;

    // ===== P0: n0 = tanh([A | h0] @ W0^T + b0)
    f32x4 acc[2][2];
    {
      float bf0 = (float)b0p.x, bf1 = (float)b0p.y;
      acc[0][0] = (f32x4){bf0, bf0, bf0, bf0};
      acc[0][1] = (f32x4){bf1, bf1, bf1, bf1};
      acc[1][0] = acc[0][0];
      acc[1][1] = acc[0][1];
    }
    // h0 part (K=128, always)
#pragma unroll
    for (int kc = 0; kc < 4; ++kc) {
      int gk = kc * 4 + q;
      f16x8 ah[2];
#pragma unroll
      for (int mt = 0; mt < 2; ++mt) {
        int row = mg * 32 + mt * 16 + colL;
        ah[mt] = *(const f16x8*)&n0rd[row * 128 + ((gk ^ (row & 7)) << 3)];
      }
#pragma unroll
      for (int mt = 0; mt < 2; ++mt)
#pragma unroll
        for (int nt = 0; nt < 2; ++nt)
          acc[mt][nt] = MFMAH(ah[mt], Wr[nt][2 + kc], acc[mt][nt]);
    }
    // A part (cols >= step are zero: skip chunks exactly)
    if (step > 0) {
      {
        int gk = q;  // A cols 0-31
        f16x8 ah[2];
#pragma unroll
        for (int mt = 0; mt < 2; ++mt) {
          int row = mg * 32 + mt * 16 + colL;
          ah[mt] = *(const f16x8*)&Aq[row * 64 + ((gk ^ (row & 7)) << 3)];
        }
#pragma unroll
        for (int mt = 0; mt < 2; ++mt)
#pragma unroll
          for (int nt = 0; nt < 2; ++nt)
            acc[mt][nt] = MFMAH(ah[mt], Wr[nt][0], acc[mt][nt]);
      }
      if (step > 32) {
        int gk = 4 + q;  // A cols 32-63
        f16x8 ah[2];
#pragma unroll
        for (int mt = 0; mt < 2; ++mt) {
          int row = mg * 32 + mt * 16 + colL;
          ah[mt] = *(const f16x8*)&Aq[row * 64 + ((gk ^ (row & 7)) << 3)];
        }
#pragma unroll
        for (int mt = 0; mt < 2; ++mt)
#pragma unroll
          for (int nt = 0; nt < 2; ++nt)
            acc[mt][nt] = MFMAH(ah[mt], Wr[nt][1], acc[mt][nt]);
      }
    }
#pragma unroll
    for (int mt = 0; mt < 2; ++mt)
#pragma unroll
      for (int nt = 0; nt < 2; ++nt)
#pragma unroll
        for (int rg = 0; rg < 4; ++rg) {
          float v = fast_tanh(acc[mt][nt][rg]);
          int row = mg * 32 + mt * 16 + q * 4 + rg;
          int col = (2 * ng + nt) * 16 + colL;
          n0wr[sw(row, col, 128)] = (_Float16)v;
        }
    __syncthreads();  // bar A: n0 complete

    // ===== P1: n1 = tanh([n0 | h1] @ W1^T + b1)
    f32x4 acc2[2][2];
    {
      float bf0 = (float)b1p.x, bf1 = (float)b1p.y;
      acc2[0][0] = (f32x4){bf0, bf0, bf0, bf0};
      acc2[0][1] = (f32x4){bf1, bf1, bf1, bf1};
      acc2[1][0] = acc2[0][0];
      acc2[1][1] = acc2[0][1];
    }
#pragma unroll
    for (int kc = 0; kc < 8; ++kc) {
      const _Float16* src = (kc < 4) ? n0wr : n1rd;
      int gk = (kc & 3) * 4 + q;
      f16x8 ah[2];
#pragma unroll
      for (int mt = 0; mt < 2; ++mt) {
        int row = mg * 32 + mt * 16 + colL;
        ah[mt] = *(const f16x8*)&src[row * 128 + ((gk ^ (row & 7)) << 3)];
      }
#pragma unroll
      for (int mt = 0; mt < 2; ++mt)
#pragma unroll
        for (int nt = 0; nt < 2; ++nt)
          acc2[mt][nt] = MFMAH(ah[mt], Wr[nt][6 + kc], acc2[mt][nt]);
    }
    float cwf[2] = {(float)cwp.x, (float)cwp.y};
    float pa[2][4];
#pragma unroll
    for (int mt = 0; mt < 2; ++mt)
#pragma unroll
      for (int rg = 0; rg < 4; ++rg) pa[mt][rg] = 0.f;
#pragma unroll
    for (int mt = 0; mt < 2; ++mt)
#pragma unroll
      for (int nt = 0; nt < 2; ++nt)
#pragma unroll
        for (int rg = 0; rg < 4; ++rg) {
          float v = fast_tanh(acc2[mt][nt][rg]);
          pa[mt][rg] += cwf[nt] * v;
          int row = mg * 32 + mt * 16 + q * 4 + rg;
          int col = (2 * ng + nt) * 16 + colL;
          n1wr[sw(row, col, 128)] = (_Float16)v;
        }
#pragma unroll
    for (int mt = 0; mt < 2; ++mt)
#pragma unroll
      for (int rg = 0; rg < 4; ++rg) {
        float s = pa[mt][rg];
        s += __shfl_xor(s, 1);
        s += __shfl_xor(s, 2);
        s += __shfl_xor(s, 4);
        s += __shfl_xor(s, 8);
        pa[mt][rg] = s;
      }
#pragma unroll
    for (int ii = 0; ii < 8; ++ii)
      if (colL == ii) {
        int row = mg * 32 + (ii >> 2) * 16 + q * 4 + (ii & 3);
        psum[ng * 64 + row] = pa[ii >> 2][ii & 3];
      }
    __syncthreads();  // bar B: psum + n1 complete

    {
      float s = cbias + psum[l] + psum[64 + l] + psum[128 + l] +
                psum[192 + l];
      float sg = fast_sigmoid(s);
      if (step < mval)
        Aq[l * 64 + ((((step >> 3) ^ (l & 7)) << 3) | (step & 7))] =
            (_Float16)sg;
    }
    p ^= 1;
  }
  __syncthreads();

  // ---- epilogue: write FULL 512x64 adj tile (zeros + band), coalesced.
  {
    const int qd = l & 15;
    const int rg4 = l >> 4;
    const int ii0 = node0 & 511;
    const int badj = node0 >> 9;
    for (int rb = 0; rb < 64; rb += 4) {
      int r = w * 64 + rb + rg4;
      float4 v;
      float* vp = (float*)&v;
#pragma unroll
      for (int c = 0; c < 4; ++c) {
        int n = qd * 4 + c;
        int ii = ii0 + n;
        int base = (ii - 64 > 0) ? ii - 64 : 0;
        int mv = min(ii, 64);
        int k = r - base;
        float val = 0.f;
        if (k >= 0 && k < mv) val = (float)Aq[sw(n, k, 64)];
        vp[c] = val;
      }
      *(float4*)&adj[((size_t)badj * 512 + r) * 512 + ii0 + qd * 4] = v;
    }
  }
}

extern "C" void kernel_launch(void* const* d_in, const int* in_sizes, int n_in,
                              void* d_out, int out_size, void* d_ws,
                              size_t ws_size, hipStream_t stream) {
  const float* x = (const float*)d_in[0];
  const int* mask = (const int*)d_in[1];
  const float* gWih0 = (const float*)d_in[2];
  const float* gWhh0 = (const float*)d_in[3];
  const float* gbih0 = (const float*)d_in[4];
  const float* gbhh0 = (const float*)d_in[5];
  const float* gWih1 = (const float*)d_in[6];
  const float* gWhh1 = (const float*)d_in[7];
  const float* gbih1 = (const float*)d_in[8];
  const float* gbhh1 = (const float*)d_in[9];
  const float* eWih0 = (const float*)d_in[10];
  const float* eWhh0 = (const float*)d_in[11];
  const float* ebih0 = (const float*)d_in[12];
  const float* ebhh0 = (const float*)d_in[13];
  const float* eWih1 = (const float*)d_in[14];
  const float* eWhh1 = (const float*)d_in[15];
  const float* ebih1 = (const float*)d_in[16];
  const float* ebhh1 = (const float*)d_in[17];
  const float* clsW = (const float*)d_in[18];
  const float* clsb = (const float*)d_in[19];
  float* out = (float*)d_out;
  float* Y = out;
  float* adj = out + YSZ;
  float* P0 = adj;  // scratch overlay in adj region; k3 overwrites all of adj

  unsigned short* Wf = (unsigned short*)d_ws;
  hipLaunchKernelGGL(k0_prep, dim3(28), dim3(256), 0, stream, eWih0, eWhh0,
                     eWih1, eWhh1, Wf);
  hipLaunchKernelGGL(k1_gemm, dim3(256), dim3(256), 0, stream, x, gWih0,
                     gbih0, gbhh0, P0);
  hipLaunchKernelGGL(k2_v8, dim3(4), dim3(512), 0, stream, P0, gWhh0, gWih1,
                     gWhh1, gbih1, gbhh1, mask, Y);
  hipFuncSetAttribute(reinterpret_cast<const void*>(k3_edge_f16),
                      hipFuncAttributeMaxDynamicSharedMemorySize, LDSTOT);
  hipLaunchKernelGGL(k3_edge_f16, dim3(512), dim3(512), LDSTOT, stream, Y,
                     Wf, ebih0, ebhh0, ebih1, ebhh1, clsW, clsb, adj);
}

// Round 11
// 742.185 us; speedup vs baseline: 1.0692x; 1.0692x over previous
//
#include <hip/hip_runtime.h>

#define B_ 64
#define S_ 512
#define D_ 256
#define H_ 128
#define M_ 64
#define N_ (B_ * S_)                 // 32768 nodes
#define YSZ ((size_t)N_ * H_)        // 4194304 floats
#define ADJSZ ((size_t)B_ * S_ * S_) // 16777216 floats

typedef __attribute__((ext_vector_type(8))) _Float16 f16x8;
typedef __attribute__((ext_vector_type(2))) _Float16 h2;
typedef __attribute__((ext_vector_type(4))) float f32x4;

#define MFMAH(a, b, c) __builtin_amdgcn_mfma_f32_16x16x32_f16(a, b, c, 0, 0, 0)

// weight frag store: 8 n-tiles x 14 k-chunks, 64 lanes x 16B each (f16)
#define WFRAGS (8 * 14)
#define WBYTES ((size_t)WFRAGS * 64 * 16)  // 114688

__device__ __forceinline__ float fast_tanh(float x) {
  float cx = __builtin_amdgcn_fmed3f(x, -10.0f, 10.0f);
  float e = __builtin_amdgcn_exp2f(cx * 2.8853900817779268f);
  float r = __builtin_amdgcn_rcpf(e + 1.0f);
  return fmaf(-2.0f, r, 1.0f);
}
__device__ __forceinline__ float fast_sigmoid(float x) {
  float cx = __builtin_amdgcn_fmed3f(x, -30.0f, 30.0f);
  float e = __builtin_amdgcn_exp2f(cx * -1.4426950408889634f);
  return __builtin_amdgcn_rcpf(1.0f + e);
}

// element index in a [rows][Kc] f16 array, XOR-swizzled 16B (8-elem) granules
__device__ __forceinline__ int sw(int row, int col, int Kc) {
  return row * Kc + ((((col >> 3) ^ (row & 7)) << 3) | (col & 7));
}
// granule-index form for [16][128] state arrays (g = 8-elem granule 0..15)
__device__ __forceinline__ int swu(int row, int g) {
  return row * 128 + (((g ^ (row & 7)) << 3));
}

__device__ __forceinline__ f16x8 pack8(float4 a, float4 b) {
  f16x8 r;
  r[0] = (_Float16)a.x; r[1] = (_Float16)a.y;
  r[2] = (_Float16)a.z; r[3] = (_Float16)a.w;
  r[4] = (_Float16)b.x; r[5] = (_Float16)b.y;
  r[6] = (_Float16)b.z; r[7] = (_Float16)b.w;
  return r;
}

// ---------------- K0: pack f16 weight fragments (native MFMA B-frag order)
__global__ __launch_bounds__(256) void k0_prep(
    const float* __restrict__ eWih0, const float* __restrict__ eWhh0,
    const float* __restrict__ eWih1, const float* __restrict__ eWhh1,
    unsigned short* __restrict__ Wf) {
  int t = blockIdx.x * 256 + threadIdx.x;
  if (t >= WFRAGS * 64) return;
  int fid = t >> 6, lane = t & 63;
  int ntg = fid / 14, kc = fid % 14;
  int j = ntg * 16 + (lane & 15);
  int kbase = (kc < 6 ? kc : kc - 6) * 32 + (lane >> 4) * 8;
  unsigned pk[4];
#pragma unroll
  for (int ii = 0; ii < 4; ++ii) {
    unsigned p2 = 0;
#pragma unroll
    for (int s = 0; s < 2; ++s) {
      int k = kbase + ii * 2 + s;
      float wv;
      if (kc < 6)
        wv = (k < 64) ? eWih0[j * 64 + k] : eWhh0[j * 128 + (k - 64)];
      else
        wv = (k < 128) ? eWih1[j * 128 + k] : eWhh1[j * 128 + (k - 128)];
      _Float16 h = (_Float16)wv;
      unsigned short us = *(unsigned short*)&h;
      p2 |= ((unsigned)us) << (16 * s);
    }
    pk[ii] = p2;
  }
  ((uint4*)Wf)[fid * 64 + lane] = make_uint4(pk[0], pk[1], pk[2], pk[3]);
}

// ------------------------------------------- K1: P0 = x @ Wih0^T + (bih0+bhh0)
__global__ __launch_bounds__(256) void k1_gemm(
    const float* __restrict__ x, const float* __restrict__ W,
    const float* __restrict__ bih, const float* __restrict__ bhh,
    float* __restrict__ P0) {
  __shared__ float Xs[32][132];
  __shared__ float Ws[32][132];
  const int t = threadIdx.x;
  const int ty = t >> 4, tx = t & 15;
  const int n0 = blockIdx.x * 128;
  float acc[8][8];
#pragma unroll
  for (int i = 0; i < 8; ++i)
#pragma unroll
    for (int j = 0; j < 8; ++j) acc[i][j] = 0.f;

  for (int kc = 0; kc < 256; kc += 32) {
    __syncthreads();
#pragma unroll
    for (int l = 0; l < 4; ++l) {
      int idx = t + l * 256;
      int r = idx >> 3, f4 = idx & 7;
      float4 v = *(const float4*)&x[(size_t)(n0 + r) * 256 + kc + f4 * 4];
      Xs[f4 * 4 + 0][r] = v.x; Xs[f4 * 4 + 1][r] = v.y;
      Xs[f4 * 4 + 2][r] = v.z; Xs[f4 * 4 + 3][r] = v.w;
      float4 wv = *(const float4*)&W[(size_t)r * 256 + kc + f4 * 4];
      Ws[f4 * 4 + 0][r] = wv.x; Ws[f4 * 4 + 1][r] = wv.y;
      Ws[f4 * 4 + 2][r] = wv.z; Ws[f4 * 4 + 3][r] = wv.w;
    }
    __syncthreads();
#pragma unroll
    for (int kk = 0; kk < 32; ++kk) {
      float4 xa = *(const float4*)&Xs[kk][ty * 8];
      float4 xb = *(const float4*)&Xs[kk][ty * 8 + 4];
      float4 wa = *(const float4*)&Ws[kk][tx * 8];
      float4 wb = *(const float4*)&Ws[kk][tx * 8 + 4];
      float xr[8] = {xa.x, xa.y, xa.z, xa.w, xb.x, xb.y, xb.z, xb.w};
      float wr[8] = {wa.x, wa.y, wa.z, wa.w, wb.x, wb.y, wb.z, wb.w};
#pragma unroll
      for (int i = 0; i < 8; ++i)
#pragma unroll
        for (int j = 0; j < 8; ++j) acc[i][j] += xr[i] * wr[j];
    }
  }
  float bias[8];
#pragma unroll
  for (int j = 0; j < 8; ++j) bias[j] = bih[tx * 8 + j] + bhh[tx * 8 + j];
#pragma unroll
  for (int i = 0; i < 8; ++i) {
    float4 s0 = make_float4(acc[i][0] + bias[0], acc[i][1] + bias[1],
                            acc[i][2] + bias[2], acc[i][3] + bias[3]);
    float4 s1 = make_float4(acc[i][4] + bias[4], acc[i][5] + bias[5],
                            acc[i][6] + bias[6], acc[i][7] + bias[7]);
    size_t base = (size_t)(n0 + ty * 8 + i) * 128 + tx * 8;
    *(float4*)&P0[base] = s0;
    *(float4*)&P0[base + 4] = s1;
  }
}

// ------------------------- K2 v7 (restored — v8's split-accumulator variant
// regressed ~230->~290us): batched-MFMA graph RNN, 8 waves; waves 0-3 = L0,
// 4-7 = L1 pipelined; 1 barrier/step.
#define K2STEP(S, PP)                                                         \
  {                                                                           \
    if (isL0 && (S) < 512) {                                                  \
      const int rd0 = ((S)&1) ^ 1;                                            \
      f32x4 acc[2];                                                           \
      _Pragma("unroll") for (int i = 0; i < 2; ++i)                           \
          acc[i] = __builtin_bit_cast(f32x4, PP[i]);                          \
      _Pragma("unroll") for (int kc = 0; kc < 4; ++kc) {                      \
        f16x8 bf = *(const f16x8*)&h0s[rd0][swu(colB, kc * 4 + q)];           \
        _Pragma("unroll") for (int i = 0; i < 2; ++i)                         \
            acc[i] = MFMAH(WA[i][kc], bf, acc[i]);                            \
      }                                                                       \
      int tn = ((S) + 2 < 512) ? (S) + 2 : 511;                               \
      _Pragma("unroll") for (int i = 0; i < 2; ++i)                           \
          PP[i] = *(const float4*)(p0base[i] + (size_t)tn * 128);             \
      _Pragma("unroll") for (int i = 0; i < 2; ++i) {                         \
        float v0 = fast_tanh(acc[i][0]), v1 = fast_tanh(acc[i][1]);           \
        float v2 = fast_tanh(acc[i][2]), v3 = fast_tanh(acc[i][3]);           \
        int nb = (wl * 2 + i) * 16 + q * 4;                                   \
        int g = nb >> 3;                                                      \
        int idx = colB * 128 + (((g ^ (colB & 7)) << 3) | (nb & 7));          \
        h2 lo = {(_Float16)v0, (_Float16)v1};                                 \
        h2 hi = {(_Float16)v2, (_Float16)v3};                                 \
        uint2 u = {__builtin_bit_cast(unsigned, lo),                          \
                   __builtin_bit_cast(unsigned, hi)};                         \
        *(uint2*)&h0s[(S)&1][idx] = u;                                        \
      }                                                                       \
    } else if (!isL0 && (S) >= 1) {                                           \
      const int t = (S)-1;                                                    \
      const int rb = t & 1;                                                   \
      f32x4 acc[2];                                                           \
      _Pragma("unroll") for (int i = 0; i < 2; ++i) acc[i] = b1v[i];          \
      _Pragma("unroll") for (int kc = 0; kc < 4; ++kc) {                      \
        f16x8 bf = *(const f16x8*)&h0s[rb][swu(colB, kc * 4 + q)];            \
        _Pragma("unroll") for (int i = 0; i < 2; ++i)                         \
            acc[i] = MFMAH(WA[i][kc], bf, acc[i]);                            \
      }                                                                       \
      _Pragma("unroll") for (int kc = 0; kc < 4; ++kc) {                      \
        f16x8 bf = *(const f16x8*)&h1s[rb ^ 1][swu(colB, kc * 4 + q)];        \
        _Pragma("unroll") for (int i = 0; i < 2; ++i)                         \
            acc[i] = MFMAH(WB[i][kc], bf, acc[i]);                            \
      }                                                                       \
      float m = mk[colB][t];                                                  \
      _Pragma("unroll") for (int i = 0; i < 2; ++i) {                         \
        float v0 = fast_tanh(acc[i][0]), v1 = fast_tanh(acc[i][1]);           \
        float v2 = fast_tanh(acc[i][2]), v3 = fast_tanh(acc[i][3]);           \
        int nb = (wl * 2 + i) * 16 + q * 4;                                   \
        int g = nb >> 3;                                                      \
        int idx = colB * 128 + (((g ^ (colB & 7)) << 3) | (nb & 7));          \
        h2 lo = {(_Float16)v0, (_Float16)v1};                                 \
        h2 hi = {(_Float16)v2, (_Float16)v3};                                 \
        uint2 u = {__builtin_bit_cast(unsigned, lo),                          \
                   __builtin_bit_cast(unsigned, hi)};                         \
        *(uint2*)&h1s[rb][idx] = u;                                           \
        float4 yv = {v0 * m, v1 * m, v2 * m, v3 * m};                         \
        *(float4*)&Y[((size_t)(b0 + colB) * 512 + t) * 128 + nb] = yv;        \
      }                                                                       \
    }                                                                         \
    __syncthreads();                                                          \
  }

__global__ __launch_bounds__(512, 1) void k2_v7(
    const float* __restrict__ P0, const float* __restrict__ Whh0,
    const float* __restrict__ Wih1, const float* __restrict__ Whh1,
    const float* __restrict__ bih1, const float* __restrict__ bhh1,
    const int* __restrict__ mask, float* __restrict__ Y) {
  __shared__ _Float16 h0s[2][16 * 128];
  __shared__ _Float16 h1s[2][16 * 128];
  __shared__ float mk[16][516];  // padded stride
  const int tid = threadIdx.x;
  const int w = tid >> 6, l = tid & 63;
  const int b0 = blockIdx.x * 16;
  const int colB = l & 15;
  const int q = l >> 4;
  const bool isL0 = (w < 4);
  const int wl = isL0 ? w : (w - 4);

  for (int i = tid; i < 16 * 512; i += 512) {
    int bb = i >> 9, t = i & 511;
    mk[bb][t] = (float)mask[(b0 + bb) * 512 + t];
  }
  for (int i = tid; i < 1024; i += 512) {
    ((unsigned*)&h0s[1][0])[i] = 0u;
    ((unsigned*)&h1s[1][0])[i] = 0u;
  }

  f16x8 WA[2][4];  // L0: Whh0 ; L1: Wih1
  f16x8 WB[2][4];  // L1 only: Whh1
  {
    const float* src = isL0 ? Whh0 : Wih1;
#pragma unroll
    for (int i = 0; i < 2; ++i)
#pragma unroll
      for (int kc = 0; kc < 4; ++kc) {
        const float* r =
            src + ((wl * 2 + i) * 16 + colB) * 128 + kc * 32 + q * 8;
        WA[i][kc] = pack8(*(const float4*)r, *(const float4*)(r + 4));
      }
    if (!isL0) {
#pragma unroll
      for (int i = 0; i < 2; ++i)
#pragma unroll
        for (int kc = 0; kc < 4; ++kc) {
          const float* r =
              Whh1 + ((wl * 2 + i) * 16 + colB) * 128 + kc * 32 + q * 8;
          WB[i][kc] = pack8(*(const float4*)r, *(const float4*)(r + 4));
        }
    }
  }
  f32x4 b1v[2];
  const float* p0base[2];
#pragma unroll
  for (int i = 0; i < 2; ++i) {
    int nb = (wl * 2 + i) * 16 + q * 4;
    if (!isL0) {
      b1v[i] = (f32x4){bih1[nb] + bhh1[nb], bih1[nb + 1] + bhh1[nb + 1],
                       bih1[nb + 2] + bhh1[nb + 2], bih1[nb + 3] + bhh1[nb + 3]};
    } else {
      b1v[i] = (f32x4){0.f, 0.f, 0.f, 0.f};
    }
    p0base[i] = P0 + (size_t)(b0 + colB) * 512 * 128 + nb;
  }
  float4 pp0[2], pp1[2];
  if (isL0) {
#pragma unroll
    for (int i = 0; i < 2; ++i) {
      pp0[i] = *(const float4*)(p0base[i]);
      pp1[i] = *(const float4*)(p0base[i] + 128);
    }
  }
  __syncthreads();

  for (int s2 = 0; s2 < 512; s2 += 2) {
    K2STEP(s2, pp0);
    K2STEP(s2 + 1, pp1);
  }
  K2STEP(512, pp0);  // epilogue: L1 computes t=511
}

// ------------------------- K3 v9: edge RNN, f16 MFMA, 8 waves, 2m x 2n/wave.
// vs v8: state double-buffers replaced by a 3-BUFFER ROTATION
// (n0rd=a, n0wr=b, n1rd=c, n1wr=a; rotate (a,b,c)<-(b,c,a)) — hazard-free
// with the existing 2 barriers. LDS 75776 -> 58368 B so 2 blocks/CU co-fit
// (R10: VGPR trim to 104 alone did NOT raise occupancy -> LDS was the limit).
#define LDSA 0       // A     [64][64] f16          :  8192 B
#define LDSR 8192    // 3 x [64][128] f16 state     : 49152 B
#define LDSPS 57344  // psum  [4][64] f32           :  1024 B
#define LDSTOT 58368

__global__ __launch_bounds__(512, 2) void k3_edge_f16(
    const float* __restrict__ Y, const unsigned short* __restrict__ Wf,
    const float* __restrict__ bih0, const float* __restrict__ bhh0,
    const float* __restrict__ bih1, const float* __restrict__ bhh1,
    const float* __restrict__ clsW, const float* __restrict__ clsb,
    float* __restrict__ adj) {
  extern __shared__ char sm[];
  _Float16* Aq = (_Float16*)(sm + LDSA);
  _Float16* Rb = (_Float16*)(sm + LDSR);  // 3 x 8192 f16 buffers
  float* psum = (float*)(sm + LDSPS);

  const int tid = threadIdx.x;
  const int w = tid >> 6, l = tid & 63;
  const int mg = w & 1, ng = w >> 1;
  const int colL = l & 15, q = l >> 4;
  const int node0 = blockIdx.x * 64;

  // init: A = 0, R0 = f16(Y) swizzled (n0rd at step 0), R2 = 0 (n1rd at 0)
  for (int i = tid; i < 2048; i += 512) ((unsigned*)(sm + LDSA))[i] = 0u;
  for (int i = tid; i < 4096; i += 512)
    ((unsigned*)(Rb + 2 * 8192))[i] = 0u;
  for (int i = tid; i < 8192; i += 512) {
    int nn = i >> 7, k = i & 127;
    float v = Y[(size_t)(node0 + nn) * 128 + k];
    Rb[sw(nn, k, 128)] = (_Float16)v;
  }

  f16x8 Wr[2][14];
#pragma unroll
  for (int nt = 0; nt < 2; ++nt)
#pragma unroll
    for (int kc = 0; kc < 14; ++kc)
      Wr[nt][kc] =
          ((const f16x8*)Wf)[(size_t)(((2 * ng + nt) * 14) + kc) * 64 + l];

  // per-lane constants packed f16 (reg trim)
  h2 b0p, b1p, cwp;
  {
    int cg0 = (2 * ng) * 16 + colL, cg1 = (2 * ng + 1) * 16 + colL;
    b0p.x = (_Float16)(bih0[cg0] + bhh0[cg0]);
    b0p.y = (_Float16)(bih0[cg1] + bhh0[cg1]);
    b1p.x = (_Float16)(bih1[cg0] + bhh1[cg0]);
    b1p.y = (_Float16)(bih1[cg1] + bhh1[cg1]);
    cwp.x = (_Float16)clsW[cg0];
    cwp.y = (_Float16)clsW[cg1];
  }
  const float cbias = clsb[0];
  const int mval = min((node0 & 511) + l, 64);

  __syncthreads();

  int ba = 0, bb = 1, bc = 2;  // buffer rotation indices (uniform)
  for (int step = 0; step < 64; ++step) {
    _Float16* n0rd = Rb + ba * 8192;
    _Float16* n0wr = Rb + bb * 8192;
    _Float16* n1rd = Rb + bc * 8192;
    _Float16* n1wr = Rb + ba * 8192;  // reuses n0rd's buffer (safe: post barA)

    // ===== P0: n0 = tanh([A | h0] @ W0^T + b0)
    f32x4 acc[2][2];
    {
      float bf0 = (float)b0p.x, bf1 = (float)b0p.y;
      acc[0][0] = (f32x4){bf0, bf0, bf0, bf0};
      acc[0][1] = (f32x4){bf1, bf1, bf1, bf1};
      acc[1][0] = acc[0][0];
      acc[1][1] = acc[0][1];
    }
    // h0 part (K=128, always)
#pragma unroll
    for (int kc = 0; kc < 4; ++kc) {
      int gk = kc * 4 + q;
      f16x8 ah[2];
#pragma unroll
      for (int mt = 0; mt < 2; ++mt) {
        int row = mg * 32 + mt * 16 + colL;
        ah[mt] = *(const f16x8*)&n0rd[row * 128 + ((gk ^ (row & 7)) << 3)];
      }
#pragma unroll
      for (int mt = 0; mt < 2; ++mt)
#pragma unroll
        for (int nt = 0; nt < 2; ++nt)
          acc[mt][nt] = MFMAH(ah[mt], Wr[nt][2 + kc], acc[mt][nt]);
    }
    // A part (cols >= step are zero: skip chunks exactly)
    if (step > 0) {
      {
        int gk = q;  // A cols 0-31
        f16x8 ah[2];
#pragma unroll
        for (int mt = 0; mt < 2; ++mt) {
          int row = mg * 32 + mt * 16 + colL;
          ah[mt] = *(const f16x8*)&Aq[row * 64 + ((gk ^ (row & 7)) << 3)];
        }
#pragma unroll
        for (int mt = 0; mt < 2; ++mt)
#pragma unroll
          for (int nt = 0; nt < 2; ++nt)
            acc[mt][nt] = MFMAH(ah[mt], Wr[nt][0], acc[mt][nt]);
      }
      if (step > 32) {
        int gk = 4 + q;  // A cols 32-63
        f16x8 ah[2];
#pragma unroll
        for (int mt = 0; mt < 2; ++mt) {
          int row = mg * 32 + mt * 16 + colL;
          ah[mt] = *(const f16x8*)&Aq[row * 64 + ((gk ^ (row & 7)) << 3)];
        }
#pragma unroll
        for (int mt = 0; mt < 2; ++mt)
#pragma unroll
          for (int nt = 0; nt < 2; ++nt)
            acc[mt][nt] = MFMAH(ah[mt], Wr[nt][1], acc[mt][nt]);
      }
    }
#pragma unroll
    for (int mt = 0; mt < 2; ++mt)
#pragma unroll
      for (int nt = 0; nt < 2; ++nt)
#pragma unroll
        for (int rg = 0; rg < 4; ++rg) {
          float v = fast_tanh(acc[mt][nt][rg]);
          int row = mg * 32 + mt * 16 + q * 4 + rg;
          int col = (2 * ng + nt) * 16 + colL;
          n0wr[sw(row, col, 128)] = (_Float16)v;
        }
    __syncthreads();  // bar A: n0 complete; n0rd buffer now reusable

    // ===== P1: n1 = tanh([n0 | h1] @ W1^T + b1)
    f32x4 acc2[2][2];
    {
      float bf0 = (float)b1p.x, bf1 = (float)b1p.y;
      acc2[0][0] = (f32x4){bf0, bf0, bf0, bf0};
      acc2[0][1] = (f32x4){bf1, bf1, bf1, bf1};
      acc2[1][0] = acc2[0][0];
      acc2[1][1] = acc2[0][1];
    }
#pragma unroll
    for (int kc = 0; kc < 8; ++kc) {
      const _Float16* src = (kc < 4) ? n0wr : n1rd;
      int gk = (kc & 3) * 4 + q;
      f16x8 ah[2];
#pragma unroll
      for (int mt = 0; mt < 2; ++mt) {
        int row = mg * 32 + mt * 16 + colL;
        ah[mt] = *(const f16x8*)&src[row * 128 + ((gk ^ (row & 7)) << 3)];
      }
#pragma unroll
      for (int mt = 0; mt < 2; ++mt)
#pragma unroll
        for (int nt = 0; nt < 2; ++nt)
          acc2[mt][nt] = MFMAH(ah[mt], Wr[nt][6 + kc], acc2[mt][nt]);
    }
    float cwf[2] = {(float)cwp.x, (float)cwp.y};
    float pa[2][4];
#pragma unroll
    for (int mt = 0; mt < 2; ++mt)
#pragma unroll
      for (int rg = 0; rg < 4; ++rg) pa[mt][rg] = 0.f;
#pragma unroll
    for (int mt = 0; mt < 2; ++mt)
#pragma unroll
      for (int nt = 0; nt < 2; ++nt)
#pragma unroll
        for (int rg = 0; rg < 4; ++rg) {
          float v = fast_tanh(acc2[mt][nt][rg]);
          pa[mt][rg] += cwf[nt] * v;
          int row = mg * 32 + mt * 16 + q * 4 + rg;
          int col = (2 * ng + nt) * 16 + colL;
          n1wr[sw(row, col, 128)] = (_Float16)v;
        }
#pragma unroll
    for (int mt = 0; mt < 2; ++mt)
#pragma unroll
      for (int rg = 0; rg < 4; ++rg) {
        float s = pa[mt][rg];
        s += __shfl_xor(s, 1);
        s += __shfl_xor(s, 2);
        s += __shfl_xor(s, 4);
        s += __shfl_xor(s, 8);
        pa[mt][rg] = s;
      }
#pragma unroll
    for (int ii = 0; ii < 8; ++ii)
      if (colL == ii) {
        int row = mg * 32 + (ii >> 2) * 16 + q * 4 + (ii & 3);
        psum[ng * 64 + row] = pa[ii >> 2][ii & 3];
      }
    __syncthreads();  // bar B: psum + n1 complete

    {
      float s = cbias + psum[l] + psum[64 + l] + psum[128 + l] +
                psum[192 + l];
      float sg = fast_sigmoid(s);
      if (step < mval)
        Aq[l * 64 + ((((step >> 3) ^ (l & 7)) << 3) | (step & 7))] =
            (_Float16)sg;
    }
    // rotate buffers: (a,b,c) <- (b,c,a)
    int tmp = ba; ba = bb; bb = bc; bc = tmp;
  }
  __syncthreads();

  // ---- epilogue: write FULL 512x64 adj tile (zeros + band), coalesced.
  {
    const int qd = l & 15;
    const int rg4 = l >> 4;
    const int ii0 = node0 & 511;
    const int badj = node0 >> 9;
    for (int rb = 0; rb < 64; rb += 4) {
      int r = w * 64 + rb + rg4;
      float4 v;
      float* vp = (float*)&v;
#pragma unroll
      for (int c = 0; c < 4; ++c) {
        int n = qd * 4 + c;
        int ii = ii0 + n;
        int base = (ii - 64 > 0) ? ii - 64 : 0;
        int mv = min(ii, 64);
        int k = r - base;
        float val = 0.f;
        if (k >= 0 && k < mv) val = (float)Aq[sw(n, k, 64)];
        vp[c] = val;
      }
      *(float4*)&adj[((size_t)badj * 512 + r) * 512 + ii0 + qd * 4] = v;
    }
  }
}

extern "C" void kernel_launch(void* const* d_in, const int* in_sizes, int n_in,
                              void* d_out, int out_size, void* d_ws,
                              size_t ws_size, hipStream_t stream) {
  const float* x = (const float*)d_in[0];
  const int* mask = (const int*)d_in[1];
  const float* gWih0 = (const float*)d_in[2];
  const float* gWhh0 = (const float*)d_in[3];
  const float* gbih0 = (const float*)d_in[4];
  const float* gbhh0 = (const float*)d_in[5];
  const float* gWih1 = (const float*)d_in[6];
  const float* gWhh1 = (const float*)d_in[7];
  const float* gbih1 = (const float*)d_in[8];
  const float* gbhh1 = (const float*)d_in[9];
  const float* eWih0 = (const float*)d_in[10];
  const float* eWhh0 = (const float*)d_in[11];
  const float* ebih0 = (const float*)d_in[12];
  const float* ebhh0 = (const float*)d_in[13];
  const float* eWih1 = (const float*)d_in[14];
  const float* eWhh1 = (const float*)d_in[15];
  const float* ebih1 = (const float*)d_in[16];
  const float* ebhh1 = (const float*)d_in[17];
  const float* clsW = (const float*)d_in[18];
  const float* clsb = (const float*)d_in[19];
  float* out = (float*)d_out;
  float* Y = out;
  float* adj = out + YSZ;
  float* P0 = adj;  // scratch overlay in adj region; k3 overwrites all of adj

  unsigned short* Wf = (unsigned short*)d_ws;
  hipLaunchKernelGGL(k0_prep, dim3(28), dim3(256), 0, stream, eWih0, eWhh0,
                     eWih1, eWhh1, Wf);
  hipLaunchKernelGGL(k1_gemm, dim3(256), dim3(256), 0, stream, x, gWih0,
                     gbih0, gbhh0, P0);
  hipLaunchKernelGGL(k2_v7, dim3(4), dim3(512), 0, stream, P0, gWhh0, gWih1,
                     gWhh1, gbih1, gbhh1, mask, Y);
  hipFuncSetAttribute(reinterpret_cast<const void*>(k3_edge_f16),
                      hipFuncAttributeMaxDynamicSharedMemorySize, LDSTOT);
  hipLaunchKernelGGL(k3_edge_f16, dim3(512), dim3(512), LDSTOT, stream, Y,
                     Wf, ebih0, ebhh0, ebih1, ebhh1, clsW, clsb, adj);
}

// Round 12
// 727.925 us; speedup vs baseline: 1.0901x; 1.0196x over previous
//
#include <hip/hip_runtime.h>

#define B_ 64
#define S_ 512
#define D_ 256
#define H_ 128
#define M_ 64
#define N_ (B_ * S_)                 // 32768 nodes
#define YSZ ((size_t)N_ * H_)        // 4194304 floats
#define ADJSZ ((size_t)B_ * S_ * S_) // 16777216 floats

typedef __attribute__((ext_vector_type(8))) _Float16 f16x8;
typedef __attribute__((ext_vector_type(2))) _Float16 h2;
typedef __attribute__((ext_vector_type(4))) float f32x4;

#define MFMAH(a, b, c) __builtin_amdgcn_mfma_f32_16x16x32_f16(a, b, c, 0, 0, 0)

// LDS-only barrier: __syncthreads() drains vmcnt(0) too, putting global
// store/prefetch latency on every step's critical path. This orders LDS only.
#define BARL() asm volatile("s_waitcnt lgkmcnt(0)\n\ts_barrier" ::: "memory")

// weight frag store: 8 n-tiles x 14 k-chunks, 64 lanes x 16B each (f16)
#define WFRAGS (8 * 14)
#define WBYTES ((size_t)WFRAGS * 64 * 16)  // 114688

__device__ __forceinline__ float fast_tanh(float x) {
  float cx = __builtin_amdgcn_fmed3f(x, -10.0f, 10.0f);
  float e = __builtin_amdgcn_exp2f(cx * 2.8853900817779268f);
  float r = __builtin_amdgcn_rcpf(e + 1.0f);
  return fmaf(-2.0f, r, 1.0f);
}
__device__ __forceinline__ float fast_sigmoid(float x) {
  float cx = __builtin_amdgcn_fmed3f(x, -30.0f, 30.0f);
  float e = __builtin_amdgcn_exp2f(cx * -1.4426950408889634f);
  return __builtin_amdgcn_rcpf(1.0f + e);
}

// element index in a [rows][Kc] f16 array, XOR-swizzled 16B (8-elem) granules
__device__ __forceinline__ int sw(int row, int col, int Kc) {
  return row * Kc + ((((col >> 3) ^ (row & 7)) << 3) | (col & 7));
}
// granule-index form for [16][128] state arrays (g = 8-elem granule 0..15)
__device__ __forceinline__ int swu(int row, int g) {
  return row * 128 + (((g ^ (row & 7)) << 3));
}

__device__ __forceinline__ f16x8 pack8(float4 a, float4 b) {
  f16x8 r;
  r[0] = (_Float16)a.x; r[1] = (_Float16)a.y;
  r[2] = (_Float16)a.z; r[3] = (_Float16)a.w;
  r[4] = (_Float16)b.x; r[5] = (_Float16)b.y;
  r[6] = (_Float16)b.z; r[7] = (_Float16)b.w;
  return r;
}

// ---------------- K0: pack f16 weight fragments (native MFMA B-frag order)
__global__ __launch_bounds__(256) void k0_prep(
    const float* __restrict__ eWih0, const float* __restrict__ eWhh0,
    const float* __restrict__ eWih1, const float* __restrict__ eWhh1,
    unsigned short* __restrict__ Wf) {
  int t = blockIdx.x * 256 + threadIdx.x;
  if (t >= WFRAGS * 64) return;
  int fid = t >> 6, lane = t & 63;
  int ntg = fid / 14, kc = fid % 14;
  int j = ntg * 16 + (lane & 15);
  int kbase = (kc < 6 ? kc : kc - 6) * 32 + (lane >> 4) * 8;
  unsigned pk[4];
#pragma unroll
  for (int ii = 0; ii < 4; ++ii) {
    unsigned p2 = 0;
#pragma unroll
    for (int s = 0; s < 2; ++s) {
      int k = kbase + ii * 2 + s;
      float wv;
      if (kc < 6)
        wv = (k < 64) ? eWih0[j * 64 + k] : eWhh0[j * 128 + (k - 64)];
      else
        wv = (k < 128) ? eWih1[j * 128 + k] : eWhh1[j * 128 + (k - 128)];
      _Float16 h = (_Float16)wv;
      unsigned short us = *(unsigned short*)&h;
      p2 |= ((unsigned)us) << (16 * s);
    }
    pk[ii] = p2;
  }
  ((uint4*)Wf)[fid * 64 + lane] = make_uint4(pk[0], pk[1], pk[2], pk[3]);
}

// ------------------------------------------- K1: P0 = x @ Wih0^T + (bih0+bhh0)
__global__ __launch_bounds__(256) void k1_gemm(
    const float* __restrict__ x, const float* __restrict__ W,
    const float* __restrict__ bih, const float* __restrict__ bhh,
    float* __restrict__ P0) {
  __shared__ float Xs[32][132];
  __shared__ float Ws[32][132];
  const int t = threadIdx.x;
  const int ty = t >> 4, tx = t & 15;
  const int n0 = blockIdx.x * 128;
  float acc[8][8];
#pragma unroll
  for (int i = 0; i < 8; ++i)
#pragma unroll
    for (int j = 0; j < 8; ++j) acc[i][j] = 0.f;

  for (int kc = 0; kc < 256; kc += 32) {
    __syncthreads();
#pragma unroll
    for (int l = 0; l < 4; ++l) {
      int idx = t + l * 256;
      int r = idx >> 3, f4 = idx & 7;
      float4 v = *(const float4*)&x[(size_t)(n0 + r) * 256 + kc + f4 * 4];
      Xs[f4 * 4 + 0][r] = v.x; Xs[f4 * 4 + 1][r] = v.y;
      Xs[f4 * 4 + 2][r] = v.z; Xs[f4 * 4 + 3][r] = v.w;
      float4 wv = *(const float4*)&W[(size_t)r * 256 + kc + f4 * 4];
      Ws[f4 * 4 + 0][r] = wv.x; Ws[f4 * 4 + 1][r] = wv.y;
      Ws[f4 * 4 + 2][r] = wv.z; Ws[f4 * 4 + 3][r] = wv.w;
    }
    __syncthreads();
#pragma unroll
    for (int kk = 0; kk < 32; ++kk) {
      float4 xa = *(const float4*)&Xs[kk][ty * 8];
      float4 xb = *(const float4*)&Xs[kk][ty * 8 + 4];
      float4 wa = *(const float4*)&Ws[kk][tx * 8];
      float4 wb = *(const float4*)&Ws[kk][tx * 8 + 4];
      float xr[8] = {xa.x, xa.y, xa.z, xa.w, xb.x, xb.y, xb.z, xb.w};
      float wr[8] = {wa.x, wa.y, wa.z, wa.w, wb.x, wb.y, wb.z, wb.w};
#pragma unroll
      for (int i = 0; i < 8; ++i)
#pragma unroll
        for (int j = 0; j < 8; ++j) acc[i][j] += xr[i] * wr[j];
    }
  }
  float bias[8];
#pragma unroll
  for (int j = 0; j < 8; ++j) bias[j] = bih[tx * 8 + j] + bhh[tx * 8 + j];
#pragma unroll
  for (int i = 0; i < 8; ++i) {
    float4 s0 = make_float4(acc[i][0] + bias[0], acc[i][1] + bias[1],
                            acc[i][2] + bias[2], acc[i][3] + bias[3]);
    float4 s1 = make_float4(acc[i][4] + bias[4], acc[i][5] + bias[5],
                            acc[i][6] + bias[6], acc[i][7] + bias[7]);
    size_t base = (size_t)(n0 + ty * 8 + i) * 128 + tx * 8;
    *(float4*)&P0[base] = s0;
    *(float4*)&P0[base + 4] = s1;
  }
}

// ------------------------- K2 v9: batched-MFMA graph RNN, 8 waves; waves 0-3
// = L0, 4-7 = L1 pipelined; 1 barrier/step. v9: step barrier is LDS-only
// (BARL) — __syncthreads drained vmcnt(0) every step, putting the Y store +
// P0 prefetch round-trip on the critical path (why R7's prefetch was inert).
#define K2STEP(S, PP)                                                         \
  {                                                                           \
    if (isL0 && (S) < 512) {                                                  \
      const int rd0 = ((S)&1) ^ 1;                                            \
      f32x4 acc[2];                                                           \
      _Pragma("unroll") for (int i = 0; i < 2; ++i)                           \
          acc[i] = __builtin_bit_cast(f32x4, PP[i]);                          \
      _Pragma("unroll") for (int kc = 0; kc < 4; ++kc) {                      \
        f16x8 bf = *(const f16x8*)&h0s[rd0][swu(colB, kc * 4 + q)];           \
        _Pragma("unroll") for (int i = 0; i < 2; ++i)                         \
            acc[i] = MFMAH(WA[i][kc], bf, acc[i]);                            \
      }                                                                       \
      int tn = ((S) + 2 < 512) ? (S) + 2 : 511;                               \
      _Pragma("unroll") for (int i = 0; i < 2; ++i)                           \
          PP[i] = *(const float4*)(p0base[i] + (size_t)tn * 128);             \
      _Pragma("unroll") for (int i = 0; i < 2; ++i) {                         \
        float v0 = fast_tanh(acc[i][0]), v1 = fast_tanh(acc[i][1]);           \
        float v2 = fast_tanh(acc[i][2]), v3 = fast_tanh(acc[i][3]);           \
        int nb = (wl * 2 + i) * 16 + q * 4;                                   \
        int g = nb >> 3;                                                      \
        int idx = colB * 128 + (((g ^ (colB & 7)) << 3) | (nb & 7));          \
        h2 lo = {(_Float16)v0, (_Float16)v1};                                 \
        h2 hi = {(_Float16)v2, (_Float16)v3};                                 \
        uint2 u = {__builtin_bit_cast(unsigned, lo),                          \
                   __builtin_bit_cast(unsigned, hi)};                         \
        *(uint2*)&h0s[(S)&1][idx] = u;                                        \
      }                                                                       \
    } else if (!isL0 && (S) >= 1) {                                           \
      const int t = (S)-1;                                                    \
      const int rb = t & 1;                                                   \
      f32x4 acc[2];                                                           \
      _Pragma("unroll") for (int i = 0; i < 2; ++i) acc[i] = b1v[i];          \
      _Pragma("unroll") for (int kc = 0; kc < 4; ++kc) {                      \
        f16x8 bf = *(const f16x8*)&h0s[rb][swu(colB, kc * 4 + q)];            \
        _Pragma("unroll") for (int i = 0; i < 2; ++i)                         \
            acc[i] = MFMAH(WA[i][kc], bf, acc[i]);                            \
      }                                                                       \
      _Pragma("unroll") for (int kc = 0; kc < 4; ++kc) {                      \
        f16x8 bf = *(const f16x8*)&h1s[rb ^ 1][swu(colB, kc * 4 + q)];        \
        _Pragma("unroll") for (int i = 0; i < 2; ++i)                         \
            acc[i] = MFMAH(WB[i][kc], bf, acc[i]);                            \
      }                                                                       \
      float m = mk[colB][t];                                                  \
      _Pragma("unroll") for (int i = 0; i < 2; ++i) {                         \
        float v0 = fast_tanh(acc[i][0]), v1 = fast_tanh(acc[i][1]);           \
        float v2 = fast_tanh(acc[i][2]), v3 = fast_tanh(acc[i][3]);           \
        int nb = (wl * 2 + i) * 16 + q * 4;                                   \
        int g = nb >> 3;                                                      \
        int idx = colB * 128 + (((g ^ (colB & 7)) << 3) | (nb & 7));          \
        h2 lo = {(_Float16)v0, (_Float16)v1};                                 \
        h2 hi = {(_Float16)v2, (_Float16)v3};                                 \
        uint2 u = {__builtin_bit_cast(unsigned, lo),                          \
                   __builtin_bit_cast(unsigned, hi)};                         \
        *(uint2*)&h1s[rb][idx] = u;                                           \
        float4 yv = {v0 * m, v1 * m, v2 * m, v3 * m};                         \
        *(float4*)&Y[((size_t)(b0 + colB) * 512 + t) * 128 + nb] = yv;        \
      }                                                                       \
    }                                                                         \
    BARL();                                                                   \
  }

__global__ __launch_bounds__(512, 1) void k2_v9(
    const float* __restrict__ P0, const float* __restrict__ Whh0,
    const float* __restrict__ Wih1, const float* __restrict__ Whh1,
    const float* __restrict__ bih1, const float* __restrict__ bhh1,
    const int* __restrict__ mask, float* __restrict__ Y) {
  __shared__ _Float16 h0s[2][16 * 128];
  __shared__ _Float16 h1s[2][16 * 128];
  __shared__ float mk[16][516];  // padded stride
  const int tid = threadIdx.x;
  const int w = tid >> 6, l = tid & 63;
  const int b0 = blockIdx.x * 16;
  const int colB = l & 15;
  const int q = l >> 4;
  const bool isL0 = (w < 4);
  const int wl = isL0 ? w : (w - 4);

  for (int i = tid; i < 16 * 512; i += 512) {
    int bb = i >> 9, t = i & 511;
    mk[bb][t] = (float)mask[(b0 + bb) * 512 + t];
  }
  for (int i = tid; i < 1024; i += 512) {
    ((unsigned*)&h0s[1][0])[i] = 0u;
    ((unsigned*)&h1s[1][0])[i] = 0u;
  }

  f16x8 WA[2][4];  // L0: Whh0 ; L1: Wih1
  f16x8 WB[2][4];  // L1 only: Whh1
  {
    const float* src = isL0 ? Whh0 : Wih1;
#pragma unroll
    for (int i = 0; i < 2; ++i)
#pragma unroll
      for (int kc = 0; kc < 4; ++kc) {
        const float* r =
            src + ((wl * 2 + i) * 16 + colB) * 128 + kc * 32 + q * 8;
        WA[i][kc] = pack8(*(const float4*)r, *(const float4*)(r + 4));
      }
    if (!isL0) {
#pragma unroll
      for (int i = 0; i < 2; ++i)
#pragma unroll
        for (int kc = 0; kc < 4; ++kc) {
          const float* r =
              Whh1 + ((wl * 2 + i) * 16 + colB) * 128 + kc * 32 + q * 8;
          WB[i][kc] = pack8(*(const float4*)r, *(const float4*)(r + 4));
        }
    }
  }
  f32x4 b1v[2];
  const float* p0base[2];
#pragma unroll
  for (int i = 0; i < 2; ++i) {
    int nb = (wl * 2 + i) * 16 + q * 4;
    if (!isL0) {
      b1v[i] = (f32x4){bih1[nb] + bhh1[nb], bih1[nb + 1] + bhh1[nb + 1],
                       bih1[nb + 2] + bhh1[nb + 2], bih1[nb + 3] + bhh1[nb + 3]};
    } else {
      b1v[i] = (f32x4){0.f, 0.f, 0.f, 0.f};
    }
    p0base[i] = P0 + (size_t)(b0 + colB) * 512 * 128 + nb;
  }
  float4 pp0[2], pp1[2];
  if (isL0) {
#pragma unroll
    for (int i = 0; i < 2; ++i) {
      pp0[i] = *(const float4*)(p0base[i]);
      pp1[i] = *(const float4*)(p0base[i] + 128);
    }
  }
  __syncthreads();

  for (int s2 = 0; s2 < 512; s2 += 2) {
    K2STEP(s2, pp0);
    K2STEP(s2 + 1, pp1);
  }
  K2STEP(512, pp0);  // epilogue: L1 computes t=511
}

// ------------------------- K3 v10: edge RNN, f16 MFMA, 8 waves, DUAL-GROUP.
// Each block owns TWO independent 64-node groups (128 nodes), interleaving
// both groups' reads/MFMAs/tanh in the same barrier phases: 256 blocks = ONE
// round (was 2), filling latency bubbles (no pipe was >50% busy). Weights
// shared across groups (no extra residency). 3-buffer state rotation/group.
// LDS: A 2x8K + state 6x16K + psum 2x1K = 116736 B (1 block/CU by design).
#define K3_A(g) ((_Float16*)(sm + (g) * 8192))
#define K3_R(g, i) ((_Float16*)(sm + 16384 + ((g) * 3 + (i)) * 16384))
#define K3_PS(g) ((float*)(sm + 114688 + (g) * 1024))
#define LDSTOT 116736

__global__ __launch_bounds__(512, 2) void k3_edge_f16(
    const float* __restrict__ Y, const unsigned short* __restrict__ Wf,
    const float* __restrict__ bih0, const float* __restrict__ bhh0,
    const float* __restrict__ bih1, const float* __restrict__ bhh1,
    const float* __restrict__ clsW, const float* __restrict__ clsb,
    float* __restrict__ adj) {
  extern __shared__ char sm[];
  const int tid = threadIdx.x;
  const int w = tid >> 6, l = tid & 63;
  const int mg = w & 1, ng = w >> 1;
  const int colL = l & 15, q = l >> 4;
  const int node0 = blockIdx.x * 128;

  // init: A(g)=0, R(g,2)=0 (n1rd at step 0), R(g,0)=f16(Y) swizzled
  for (int i = tid; i < 4096; i += 512) ((unsigned*)sm)[i] = 0u;
  for (int i = tid; i < 4096; i += 512) {
    ((unsigned*)K3_R(0, 2))[i] = 0u;
    ((unsigned*)K3_R(1, 2))[i] = 0u;
  }
  for (int i = tid; i < 16384; i += 512) {
    int nn = i >> 7, k = i & 127;
    float v = Y[(size_t)(node0 + nn) * 128 + k];
    K3_R(nn >> 6, 0)[sw(nn & 63, k, 128)] = (_Float16)v;
  }

  f16x8 Wr[2][14];
#pragma unroll
  for (int nt = 0; nt < 2; ++nt)
#pragma unroll
    for (int kc = 0; kc < 14; ++kc)
      Wr[nt][kc] =
          ((const f16x8*)Wf)[(size_t)(((2 * ng + nt) * 14) + kc) * 64 + l];

  // per-lane constants packed f16
  h2 b0p, b1p, cwp;
  {
    int cg0 = (2 * ng) * 16 + colL, cg1 = (2 * ng + 1) * 16 + colL;
    b0p.x = (_Float16)(bih0[cg0] + bhh0[cg0]);
    b0p.y = (_Float16)(bih0[cg1] + bhh0[cg1]);
    b1p.x = (_Float16)(bih1[cg0] + bhh1[cg0]);
    b1p.y = (_Float16)(bih1[cg1] + bhh1[cg1]);
    cwp.x = (_Float16)clsW[cg0];
    cwp.y = (_Float16)clsW[cg1];
  }
  const float cbias = clsb[0];
  int mval[2];
  mval[0] = min(((node0 + 0) & 511) + l, 64);
  mval[1] = min(((node0 + 64) & 511) + l, 64);

  __syncthreads();

  int ba = 0, bbv = 1, bc = 2;  // rotation indices (uniform)
  for (int step = 0; step < 64; ++step) {
    _Float16* n0rd[2] = {K3_R(0, 0) + ba * 0, nullptr};  // placeholders
    // (pointers assigned below with rotation applied; static g-indexing)
    _Float16* p_n0rd[2] = {K3_R(0, ba), K3_R(1, ba)};
    _Float16* p_n0wr[2] = {K3_R(0, bbv), K3_R(1, bbv)};
    _Float16* p_n1rd[2] = {K3_R(0, bc), K3_R(1, bc)};
    _Float16* p_n1wr[2] = {K3_R(0, ba), K3_R(1, ba)};
    (void)n0rd;

    // ===== P0: n0_g = tanh([A_g | h0_g] @ W0^T + b0), both groups interleaved
    f32x4 acc[2][2][2];  // [g][mt][nt]
    {
      float bf0 = (float)b0p.x, bf1 = (float)b0p.y;
#pragma unroll
      for (int g = 0; g < 2; ++g) {
        acc[g][0][0] = (f32x4){bf0, bf0, bf0, bf0};
        acc[g][0][1] = (f32x4){bf1, bf1, bf1, bf1};
        acc[g][1][0] = acc[g][0][0];
        acc[g][1][1] = acc[g][0][1];
      }
    }
#pragma unroll
    for (int kc = 0; kc < 4; ++kc) {
      int gk = kc * 4 + q;
      f16x8 ah[2][2];
#pragma unroll
      for (int g = 0; g < 2; ++g)
#pragma unroll
        for (int mt = 0; mt < 2; ++mt) {
          int row = mg * 32 + mt * 16 + colL;
          ah[g][mt] =
              *(const f16x8*)&p_n0rd[g][row * 128 + ((gk ^ (row & 7)) << 3)];
        }
#pragma unroll
      for (int g = 0; g < 2; ++g)
#pragma unroll
        for (int mt = 0; mt < 2; ++mt)
#pragma unroll
          for (int nt = 0; nt < 2; ++nt)
            acc[g][mt][nt] = MFMAH(ah[g][mt], Wr[nt][2 + kc], acc[g][mt][nt]);
    }
    if (step > 0) {
      {
        int gk = q;
        f16x8 ah[2][2];
#pragma unroll
        for (int g = 0; g < 2; ++g)
#pragma unroll
          for (int mt = 0; mt < 2; ++mt) {
            int row = mg * 32 + mt * 16 + colL;
            ah[g][mt] =
                *(const f16x8*)&K3_A(g)[row * 64 + ((gk ^ (row & 7)) << 3)];
          }
#pragma unroll
        for (int g = 0; g < 2; ++g)
#pragma unroll
          for (int mt = 0; mt < 2; ++mt)
#pragma unroll
            for (int nt = 0; nt < 2; ++nt)
              acc[g][mt][nt] = MFMAH(ah[g][mt], Wr[nt][0], acc[g][mt][nt]);
      }
      if (step > 32) {
        int gk = 4 + q;
        f16x8 ah[2][2];
#pragma unroll
        for (int g = 0; g < 2; ++g)
#pragma unroll
          for (int mt = 0; mt < 2; ++mt) {
            int row = mg * 32 + mt * 16 + colL;
            ah[g][mt] =
                *(const f16x8*)&K3_A(g)[row * 64 + ((gk ^ (row & 7)) << 3)];
          }
#pragma unroll
        for (int g = 0; g < 2; ++g)
#pragma unroll
          for (int mt = 0; mt < 2; ++mt)
#pragma unroll
            for (int nt = 0; nt < 2; ++nt)
              acc[g][mt][nt] = MFMAH(ah[g][mt], Wr[nt][1], acc[g][mt][nt]);
      }
    }
#pragma unroll
    for (int g = 0; g < 2; ++g)
#pragma unroll
      for (int mt = 0; mt < 2; ++mt)
#pragma unroll
        for (int nt = 0; nt < 2; ++nt)
#pragma unroll
          for (int rg = 0; rg < 4; ++rg) {
            float v = fast_tanh(acc[g][mt][nt][rg]);
            int row = mg * 32 + mt * 16 + q * 4 + rg;
            int col = (2 * ng + nt) * 16 + colL;
            p_n0wr[g][sw(row, col, 128)] = (_Float16)v;
          }
    __syncthreads();  // bar A

    // ===== P1: n1_g = tanh([n0_g | h1_g] @ W1^T + b1)
    f32x4 acc2[2][2][2];
    {
      float bf0 = (float)b1p.x, bf1 = (float)b1p.y;
#pragma unroll
      for (int g = 0; g < 2; ++g) {
        acc2[g][0][0] = (f32x4){bf0, bf0, bf0, bf0};
        acc2[g][0][1] = (f32x4){bf1, bf1, bf1, bf1};
        acc2[g][1][0] = acc2[g][0][0];
        acc2[g][1][1] = acc2[g][0][1];
      }
    }
#pragma unroll
    for (int kc = 0; kc < 8; ++kc) {
      int gk = (kc & 3) * 4 + q;
      f16x8 ah[2][2];
#pragma unroll
      for (int g = 0; g < 2; ++g) {
        const _Float16* src = (kc < 4) ? p_n0wr[g] : p_n1rd[g];
#pragma unroll
        for (int mt = 0; mt < 2; ++mt) {
          int row = mg * 32 + mt * 16 + colL;
          ah[g][mt] = *(const f16x8*)&src[row * 128 + ((gk ^ (row & 7)) << 3)];
        }
      }
#pragma unroll
      for (int g = 0; g < 2; ++g)
#pragma unroll
        for (int mt = 0; mt < 2; ++mt)
#pragma unroll
          for (int nt = 0; nt < 2; ++nt)
            acc2[g][mt][nt] = MFMAH(ah[g][mt], Wr[nt][6 + kc], acc2[g][mt][nt]);
    }
    float cwf[2] = {(float)cwp.x, (float)cwp.y};
    float pa[2][2][4];  // [g][mt][rg]
#pragma unroll
    for (int g = 0; g < 2; ++g)
#pragma unroll
      for (int mt = 0; mt < 2; ++mt)
#pragma unroll
        for (int rg = 0; rg < 4; ++rg) pa[g][mt][rg] = 0.f;
#pragma unroll
    for (int g = 0; g < 2; ++g)
#pragma unroll
      for (int mt = 0; mt < 2; ++mt)
#pragma unroll
        for (int nt = 0; nt < 2; ++nt)
#pragma unroll
          for (int rg = 0; rg < 4; ++rg) {
            float v = fast_tanh(acc2[g][mt][nt][rg]);
            pa[g][mt][rg] += cwf[nt] * v;
            int row = mg * 32 + mt * 16 + q * 4 + rg;
            int col = (2 * ng + nt) * 16 + colL;
            p_n1wr[g][sw(row, col, 128)] = (_Float16)v;
          }
#pragma unroll
    for (int g = 0; g < 2; ++g)
#pragma unroll
      for (int mt = 0; mt < 2; ++mt)
#pragma unroll
        for (int rg = 0; rg < 4; ++rg) {
          float s = pa[g][mt][rg];
          s += __shfl_xor(s, 1);
          s += __shfl_xor(s, 2);
          s += __shfl_xor(s, 4);
          s += __shfl_xor(s, 8);
          pa[g][mt][rg] = s;
        }
#pragma unroll
    for (int ii = 0; ii < 8; ++ii)
      if (colL == ii) {
        int row = mg * 32 + (ii >> 2) * 16 + q * 4 + (ii & 3);
        K3_PS(0)[ng * 64 + row] = pa[0][ii >> 2][ii & 3];
        K3_PS(1)[ng * 64 + row] = pa[1][ii >> 2][ii & 3];
      }
    __syncthreads();  // bar B

    // ===== cls: all waves redundantly compute both groups' sigmoids.
    {
      float* ps0 = K3_PS(0);
      float* ps1 = K3_PS(1);
      float s0 = cbias + ps0[l] + ps0[64 + l] + ps0[128 + l] + ps0[192 + l];
      float s1 = cbias + ps1[l] + ps1[64 + l] + ps1[128 + l] + ps1[192 + l];
      float sg0 = fast_sigmoid(s0);
      float sg1 = fast_sigmoid(s1);
      int aidx = l * 64 + ((((step >> 3) ^ (l & 7)) << 3) | (step & 7));
      if (step < mval[0]) K3_A(0)[aidx] = (_Float16)sg0;
      if (step < mval[1]) K3_A(1)[aidx] = (_Float16)sg1;
    }
    int tmp = ba; ba = bbv; bbv = bc; bc = tmp;
  }
  __syncthreads();

  // ---- epilogue: write both groups' FULL 512x64 adj tiles, coalesced.
#pragma unroll
  for (int g = 0; g < 2; ++g) {
    const int qd = l & 15;
    const int rg4 = l >> 4;
    const int node0g = node0 + g * 64;
    const int ii0 = node0g & 511;
    const int badj = node0g >> 9;
    _Float16* Ag = K3_A(g);
    for (int rb = 0; rb < 64; rb += 4) {
      int r = w * 64 + rb + rg4;
      float4 v;
      float* vp = (float*)&v;
#pragma unroll
      for (int c = 0; c < 4; ++c) {
        int n = qd * 4 + c;
        int ii = ii0 + n;
        int base = (ii - 64 > 0) ? ii - 64 : 0;
        int mv = min(ii, 64);
        int k = r - base;
        float val = 0.f;
        if (k >= 0 && k < mv) val = (float)Ag[sw(n, k, 64)];
        vp[c] = val;
      }
      *(float4*)&adj[((size_t)badj * 512 + r) * 512 + ii0 + qd * 4] = v;
    }
  }
}

extern "C" void kernel_launch(void* const* d_in, const int* in_sizes, int n_in,
                              void* d_out, int out_size, void* d_ws,
                              size_t ws_size, hipStream_t stream) {
  const float* x = (const float*)d_in[0];
  const int* mask = (const int*)d_in[1];
  const float* gWih0 = (const float*)d_in[2];
  const float* gWhh0 = (const float*)d_in[3];
  const float* gbih0 = (const float*)d_in[4];
  const float* gbhh0 = (const float*)d_in[5];
  const float* gWih1 = (const float*)d_in[6];
  const float* gWhh1 = (const float*)d_in[7];
  const float* gbih1 = (const float*)d_in[8];
  const float* gbhh1 = (const float*)d_in[9];
  const float* eWih0 = (const float*)d_in[10];
  const float* eWhh0 = (const float*)d_in[11];
  const float* ebih0 = (const float*)d_in[12];
  const float* ebhh0 = (const float*)d_in[13];
  const float* eWih1 = (const float*)d_in[14];
  const float* eWhh1 = (const float*)d_in[15];
  const float* ebih1 = (const float*)d_in[16];
  const float* ebhh1 = (const float*)d_in[17];
  const float* clsW = (const float*)d_in[18];
  const float* clsb = (const float*)d_in[19];
  float* out = (float*)d_out;
  float* Y = out;
  float* adj = out + YSZ;
  float* P0 = adj;  // scratch overlay in adj region; k3 overwrites all of adj

  unsigned short* Wf = (unsigned short*)d_ws;
  hipLaunchKernelGGL(k0_prep, dim3(28), dim3(256), 0, stream, eWih0, eWhh0,
                     eWih1, eWhh1, Wf);
  hipLaunchKernelGGL(k1_gemm, dim3(256), dim3(256), 0, stream, x, gWih0,
                     gbih0, gbhh0, P0);
  hipLaunchKernelGGL(k2_v9, dim3(4), dim3(512), 0, stream, P0, gWhh0, gWih1,
                     gWhh1, gbih1, gbhh1, mask, Y);
  hipFuncSetAttribute(reinterpret_cast<const void*>(k3_edge_f16),
                      hipFuncAttributeMaxDynamicSharedMemorySize, LDSTOT);
  hipLaunchKernelGGL(k3_edge_f16, dim3(256), dim3(512), LDSTOT, stream, Y,
                     Wf, ebih0, ebhh0, ebih1, ebhh1, clsW, clsb, adj);
}

// Round 13
// 598.076 us; speedup vs baseline: 1.3268x; 1.2171x over previous
//
#include <hip/hip_runtime.h>

#define B_ 64
#define S_ 512
#define D_ 256
#define H_ 128
#define M_ 64
#define N_ (B_ * S_)                 // 32768 nodes
#define YSZ ((size_t)N_ * H_)        // 4194304 floats
#define ADJSZ ((size_t)B_ * S_ * S_) // 16777216 floats

typedef __attribute__((ext_vector_type(8))) _Float16 f16x8;
typedef __attribute__((ext_vector_type(2))) _Float16 h2;
typedef __attribute__((ext_vector_type(4))) float f32x4;

#define MFMAH(a, b, c) __builtin_amdgcn_mfma_f32_16x16x32_f16(a, b, c, 0, 0, 0)

// LDS-only barrier (k2): __syncthreads() drains vmcnt(0) too.
#define BARL() asm volatile("s_waitcnt lgkmcnt(0)\n\ts_barrier" ::: "memory")

#if __has_builtin(__builtin_amdgcn_fdot2)
#define FDOT2(a, b, c) __builtin_amdgcn_fdot2((a), (b), (c), false)
#else
__device__ __forceinline__ float FDOT2(h2 a, h2 b, float c) {
  return c + (float)a.x * (float)b.x + (float)a.y * (float)b.y;
}
#endif

// weight frag store: 8 n-tiles x 14 k-chunks, 64 lanes x 16B each (f16)
#define WFRAGS (8 * 14)
#define WBYTES ((size_t)WFRAGS * 64 * 16)  // 114688

// Clamp-free: e^{2x} overflow -> rcp(inf)=0 -> tanh=+1 exactly; e->0 -> -1.
__device__ __forceinline__ float fast_tanh(float x) {
  float e = __builtin_amdgcn_exp2f(x * 2.8853900817779268f);
  float r = __builtin_amdgcn_rcpf(e + 1.0f);
  return fmaf(-2.0f, r, 1.0f);
}
__device__ __forceinline__ float fast_sigmoid(float x) {
  float e = __builtin_amdgcn_exp2f(x * -1.4426950408889634f);
  return __builtin_amdgcn_rcpf(1.0f + e);
}

// element index in a [rows][Kc] f16 array, XOR-swizzled 16B (8-elem) granules
__device__ __forceinline__ int sw(int row, int col, int Kc) {
  return row * Kc + ((((col >> 3) ^ (row & 7)) << 3) | (col & 7));
}
// granule-index form for [16][128] state arrays (g = 8-elem granule 0..15)
__device__ __forceinline__ int swu(int row, int g) {
  return row * 128 + (((g ^ (row & 7)) << 3));
}

__device__ __forceinline__ f16x8 pack8(float4 a, float4 b) {
  f16x8 r;
  r[0] = (_Float16)a.x; r[1] = (_Float16)a.y;
  r[2] = (_Float16)a.z; r[3] = (_Float16)a.w;
  r[4] = (_Float16)b.x; r[5] = (_Float16)b.y;
  r[6] = (_Float16)b.z; r[7] = (_Float16)b.w;
  return r;
}

// ---------------- K0: pack f16 weight fragments (native MFMA frag order;
// layout is symmetric for A and B operands: row/col = lane&15, k=(lane>>4)*8)
__global__ __launch_bounds__(256) void k0_prep(
    const float* __restrict__ eWih0, const float* __restrict__ eWhh0,
    const float* __restrict__ eWih1, const float* __restrict__ eWhh1,
    unsigned short* __restrict__ Wf) {
  int t = blockIdx.x * 256 + threadIdx.x;
  if (t >= WFRAGS * 64) return;
  int fid = t >> 6, lane = t & 63;
  int ntg = fid / 14, kc = fid % 14;
  int j = ntg * 16 + (lane & 15);
  int kbase = (kc < 6 ? kc : kc - 6) * 32 + (lane >> 4) * 8;
  unsigned pk[4];
#pragma unroll
  for (int ii = 0; ii < 4; ++ii) {
    unsigned p2 = 0;
#pragma unroll
    for (int s = 0; s < 2; ++s) {
      int k = kbase + ii * 2 + s;
      float wv;
      if (kc < 6)
        wv = (k < 64) ? eWih0[j * 64 + k] : eWhh0[j * 128 + (k - 64)];
      else
        wv = (k < 128) ? eWih1[j * 128 + k] : eWhh1[j * 128 + (k - 128)];
      _Float16 h = (_Float16)wv;
      unsigned short us = *(unsigned short*)&h;
      p2 |= ((unsigned)us) << (16 * s);
    }
    pk[ii] = p2;
  }
  ((uint4*)Wf)[fid * 64 + lane] = make_uint4(pk[0], pk[1], pk[2], pk[3]);
}

// ------------------------------------------- K1: P0 = x @ Wih0^T + (bih0+bhh0)
__global__ __launch_bounds__(256) void k1_gemm(
    const float* __restrict__ x, const float* __restrict__ W,
    const float* __restrict__ bih, const float* __restrict__ bhh,
    float* __restrict__ P0) {
  __shared__ float Xs[32][132];
  __shared__ float Ws[32][132];
  const int t = threadIdx.x;
  const int ty = t >> 4, tx = t & 15;
  const int n0 = blockIdx.x * 128;
  float acc[8][8];
#pragma unroll
  for (int i = 0; i < 8; ++i)
#pragma unroll
    for (int j = 0; j < 8; ++j) acc[i][j] = 0.f;

  for (int kc = 0; kc < 256; kc += 32) {
    __syncthreads();
#pragma unroll
    for (int l = 0; l < 4; ++l) {
      int idx = t + l * 256;
      int r = idx >> 3, f4 = idx & 7;
      float4 v = *(const float4*)&x[(size_t)(n0 + r) * 256 + kc + f4 * 4];
      Xs[f4 * 4 + 0][r] = v.x; Xs[f4 * 4 + 1][r] = v.y;
      Xs[f4 * 4 + 2][r] = v.z; Xs[f4 * 4 + 3][r] = v.w;
      float4 wv = *(const float4*)&W[(size_t)r * 256 + kc + f4 * 4];
      Ws[f4 * 4 + 0][r] = wv.x; Ws[f4 * 4 + 1][r] = wv.y;
      Ws[f4 * 4 + 2][r] = wv.z; Ws[f4 * 4 + 3][r] = wv.w;
    }
    __syncthreads();
#pragma unroll
    for (int kk = 0; kk < 32; ++kk) {
      float4 xa = *(const float4*)&Xs[kk][ty * 8];
      float4 xb = *(const float4*)&Xs[kk][ty * 8 + 4];
      float4 wa = *(const float4*)&Ws[kk][tx * 8];
      float4 wb = *(const float4*)&Ws[kk][tx * 8 + 4];
      float xr[8] = {xa.x, xa.y, xa.z, xa.w, xb.x, xb.y, xb.z, xb.w};
      float wr[8] = {wa.x, wa.y, wa.z, wa.w, wb.x, wb.y, wb.z, wb.w};
#pragma unroll
      for (int i = 0; i < 8; ++i)
#pragma unroll
        for (int j = 0; j < 8; ++j) acc[i][j] += xr[i] * wr[j];
    }
  }
  float bias[8];
#pragma unroll
  for (int j = 0; j < 8; ++j) bias[j] = bih[tx * 8 + j] + bhh[tx * 8 + j];
#pragma unroll
  for (int i = 0; i < 8; ++i) {
    float4 s0 = make_float4(acc[i][0] + bias[0], acc[i][1] + bias[1],
                            acc[i][2] + bias[2], acc[i][3] + bias[3]);
    float4 s1 = make_float4(acc[i][4] + bias[4], acc[i][5] + bias[5],
                            acc[i][6] + bias[6], acc[i][7] + bias[7]);
    size_t base = (size_t)(n0 + ty * 8 + i) * 128 + tx * 8;
    *(float4*)&P0[base] = s0;
    *(float4*)&P0[base + 4] = s1;
  }
}

// ------------------------- K2 v9 (stable): batched-MFMA graph RNN, 8 waves;
// waves 0-3 = L0, 4-7 = L1 pipelined; 1 LDS-only barrier/step.
#define K2STEP(S, PP)                                                         \
  {                                                                           \
    if (isL0 && (S) < 512) {                                                  \
      const int rd0 = ((S)&1) ^ 1;                                            \
      f32x4 acc[2];                                                           \
      _Pragma("unroll") for (int i = 0; i < 2; ++i)                           \
          acc[i] = __builtin_bit_cast(f32x4, PP[i]);                          \
      _Pragma("unroll") for (int kc = 0; kc < 4; ++kc) {                      \
        f16x8 bf = *(const f16x8*)&h0s[rd0][swu(colB, kc * 4 + q)];           \
        _Pragma("unroll") for (int i = 0; i < 2; ++i)                         \
            acc[i] = MFMAH(WA[i][kc], bf, acc[i]);                            \
      }                                                                       \
      int tn = ((S) + 2 < 512) ? (S) + 2 : 511;                               \
      _Pragma("unroll") for (int i = 0; i < 2; ++i)                           \
          PP[i] = *(const float4*)(p0base[i] + (size_t)tn * 128);             \
      _Pragma("unroll") for (int i = 0; i < 2; ++i) {                         \
        float v0 = fast_tanh(acc[i][0]), v1 = fast_tanh(acc[i][1]);           \
        float v2 = fast_tanh(acc[i][2]), v3 = fast_tanh(acc[i][3]);           \
        int nb = (wl * 2 + i) * 16 + q * 4;                                   \
        int g = nb >> 3;                                                      \
        int idx = colB * 128 + (((g ^ (colB & 7)) << 3) | (nb & 7));          \
        h2 lo = {(_Float16)v0, (_Float16)v1};                                 \
        h2 hi = {(_Float16)v2, (_Float16)v3};                                 \
        uint2 u = {__builtin_bit_cast(unsigned, lo),                          \
                   __builtin_bit_cast(unsigned, hi)};                         \
        *(uint2*)&h0s[(S)&1][idx] = u;                                        \
      }                                                                       \
    } else if (!isL0 && (S) >= 1) {                                           \
      const int t = (S)-1;                                                    \
      const int rb = t & 1;                                                   \
      f32x4 acc[2];                                                           \
      _Pragma("unroll") for (int i = 0; i < 2; ++i) acc[i] = b1v[i];          \
      _Pragma("unroll") for (int kc = 0; kc < 4; ++kc) {                      \
        f16x8 bf = *(const f16x8*)&h0s[rb][swu(colB, kc * 4 + q)];            \
        _Pragma("unroll") for (int i = 0; i < 2; ++i)                         \
            acc[i] = MFMAH(WA[i][kc], bf, acc[i]);                            \
      }                                                                       \
      _Pragma("unroll") for (int kc = 0; kc < 4; ++kc) {                      \
        f16x8 bf = *(const f16x8*)&h1s[rb ^ 1][swu(colB, kc * 4 + q)];        \
        _Pragma("unroll") for (int i = 0; i < 2; ++i)                         \
            acc[i] = MFMAH(WB[i][kc], bf, acc[i]);                            \
      }                                                                       \
      float m = mk[colB][t];                                                  \
      _Pragma("unroll") for (int i = 0; i < 2; ++i) {                         \
        float v0 = fast_tanh(acc[i][0]), v1 = fast_tanh(acc[i][1]);           \
        float v2 = fast_tanh(acc[i][2]), v3 = fast_tanh(acc[i][3]);           \
        int nb = (wl * 2 + i) * 16 + q * 4;                                   \
        int g = nb >> 3;                                                      \
        int idx = colB * 128 + (((g ^ (colB & 7)) << 3) | (nb & 7));          \
        h2 lo = {(_Float16)v0, (_Float16)v1};                                 \
        h2 hi = {(_Float16)v2, (_Float16)v3};                                 \
        uint2 u = {__builtin_bit_cast(unsigned, lo),                          \
                   __builtin_bit_cast(unsigned, hi)};                         \
        *(uint2*)&h1s[rb][idx] = u;                                           \
        float4 yv = {v0 * m, v1 * m, v2 * m, v3 * m};                         \
        *(float4*)&Y[((size_t)(b0 + colB) * 512 + t) * 128 + nb] = yv;        \
      }                                                                       \
    }                                                                         \
    BARL();                                                                   \
  }

__global__ __launch_bounds__(512, 1) void k2_v9(
    const float* __restrict__ P0, const float* __restrict__ Whh0,
    const float* __restrict__ Wih1, const float* __restrict__ Whh1,
    const float* __restrict__ bih1, const float* __restrict__ bhh1,
    const int* __restrict__ mask, float* __restrict__ Y) {
  __shared__ _Float16 h0s[2][16 * 128];
  __shared__ _Float16 h1s[2][16 * 128];
  __shared__ float mk[16][516];  // padded stride
  const int tid = threadIdx.x;
  const int w = tid >> 6, l = tid & 63;
  const int b0 = blockIdx.x * 16;
  const int colB = l & 15;
  const int q = l >> 4;
  const bool isL0 = (w < 4);
  const int wl = isL0 ? w : (w - 4);

  for (int i = tid; i < 16 * 512; i += 512) {
    int bb = i >> 9, t = i & 511;
    mk[bb][t] = (float)mask[(b0 + bb) * 512 + t];
  }
  for (int i = tid; i < 1024; i += 512) {
    ((unsigned*)&h0s[1][0])[i] = 0u;
    ((unsigned*)&h1s[1][0])[i] = 0u;
  }

  f16x8 WA[2][4];  // L0: Whh0 ; L1: Wih1
  f16x8 WB[2][4];  // L1 only: Whh1
  {
    const float* src = isL0 ? Whh0 : Wih1;
#pragma unroll
    for (int i = 0; i < 2; ++i)
#pragma unroll
      for (int kc = 0; kc < 4; ++kc) {
        const float* r =
            src + ((wl * 2 + i) * 16 + colB) * 128 + kc * 32 + q * 8;
        WA[i][kc] = pack8(*(const float4*)r, *(const float4*)(r + 4));
      }
    if (!isL0) {
#pragma unroll
      for (int i = 0; i < 2; ++i)
#pragma unroll
        for (int kc = 0; kc < 4; ++kc) {
          const float* r =
              Whh1 + ((wl * 2 + i) * 16 + colB) * 128 + kc * 32 + q * 8;
          WB[i][kc] = pack8(*(const float4*)r, *(const float4*)(r + 4));
        }
    }
  }
  f32x4 b1v[2];
  const float* p0base[2];
#pragma unroll
  for (int i = 0; i < 2; ++i) {
    int nb = (wl * 2 + i) * 16 + q * 4;
    if (!isL0) {
      b1v[i] = (f32x4){bih1[nb] + bhh1[nb], bih1[nb + 1] + bhh1[nb + 1],
                       bih1[nb + 2] + bhh1[nb + 2], bih1[nb + 3] + bhh1[nb + 3]};
    } else {
      b1v[i] = (f32x4){0.f, 0.f, 0.f, 0.f};
    }
    p0base[i] = P0 + (size_t)(b0 + colB) * 512 * 128 + nb;
  }
  float4 pp0[2], pp1[2];
  if (isL0) {
#pragma unroll
    for (int i = 0; i < 2; ++i) {
      pp0[i] = *(const float4*)(p0base[i]);
      pp1[i] = *(const float4*)(p0base[i] + 128);
    }
  }
  __syncthreads();

  for (int s2 = 0; s2 < 512; s2 += 2) {
    K2STEP(s2, pp0);
    K2STEP(s2 + 1, pp1);
  }
  K2STEP(512, pp0);  // epilogue: L1 computes t=511
}

// ------------------------- K3 v11: edge RNN, dual-group, OPERAND-SWAPPED MFMA.
// D = W(A) x state(B): lane now holds 4 consecutive FEATURES of one node ->
// state writes become aligned uint2 (b64) instead of 4 scattered u16; cls dot
// becomes 2 fdot2 + 2-shfl q-reduce. State reads & Wf fragments unchanged
// (A/B per-lane layouts are symmetric). Exact same math, less VALU/LDS-write.
#define K3_A(g) ((_Float16*)(sm + (g) * 8192))
#define K3_R(g, i) ((_Float16*)(sm + 16384 + ((g) * 3 + (i)) * 16384))
#define K3_PS(g) ((float*)(sm + 114688 + (g) * 1024))
#define LDSTOT 116736

__global__ __launch_bounds__(512, 2) void k3_edge_f16(
    const float* __restrict__ Y, const unsigned short* __restrict__ Wf,
    const float* __restrict__ bih0, const float* __restrict__ bhh0,
    const float* __restrict__ bih1, const float* __restrict__ bhh1,
    const float* __restrict__ clsW, const float* __restrict__ clsb,
    float* __restrict__ adj) {
  extern __shared__ char sm[];
  const int tid = threadIdx.x;
  const int w = tid >> 6, l = tid & 63;
  const int mg = w & 1, ng = w >> 1;
  const int colL = l & 15, q = l >> 4;
  const int node0 = blockIdx.x * 128;

  // init: A(g)=0, R(g,2)=0 (n1rd at step 0), R(g,0)=f16(Y) swizzled
  for (int i = tid; i < 4096; i += 512) ((unsigned*)sm)[i] = 0u;
  for (int i = tid; i < 4096; i += 512) {
    ((unsigned*)K3_R(0, 2))[i] = 0u;
    ((unsigned*)K3_R(1, 2))[i] = 0u;
  }
  for (int i = tid; i < 16384; i += 512) {
    int nn = i >> 7, k = i & 127;
    float v = Y[(size_t)(node0 + nn) * 128 + k];
    K3_R(nn >> 6, 0)[sw(nn & 63, k, 128)] = (_Float16)v;
  }

  f16x8 Wr[2][14];
#pragma unroll
  for (int nt = 0; nt < 2; ++nt)
#pragma unroll
    for (int kc = 0; kc < 14; ++kc)
      Wr[nt][kc] =
          ((const f16x8*)Wf)[(size_t)(((2 * ng + nt) * 14) + kc) * 64 + l];

  // per-lane constants in D layout: lane covers feats f0..f0+3 per nt
  f32x4 b0v[2], b1v[2];
  h2 cw2[2][2];
#pragma unroll
  for (int nt = 0; nt < 2; ++nt) {
    int f0 = (2 * ng + nt) * 16 + q * 4;
    b0v[nt] = (f32x4){bih0[f0] + bhh0[f0], bih0[f0 + 1] + bhh0[f0 + 1],
                      bih0[f0 + 2] + bhh0[f0 + 2], bih0[f0 + 3] + bhh0[f0 + 3]};
    b1v[nt] = (f32x4){bih1[f0] + bhh1[f0], bih1[f0 + 1] + bhh1[f0 + 1],
                      bih1[f0 + 2] + bhh1[f0 + 2], bih1[f0 + 3] + bhh1[f0 + 3]};
    cw2[nt][0].x = (_Float16)clsW[f0];
    cw2[nt][0].y = (_Float16)clsW[f0 + 1];
    cw2[nt][1].x = (_Float16)clsW[f0 + 2];
    cw2[nt][1].y = (_Float16)clsW[f0 + 3];
  }
  const float cbias = clsb[0];
  int mval[2];
  mval[0] = min(((node0 + 0) & 511) + l, 64);
  mval[1] = min(((node0 + 64) & 511) + l, 64);

  // step-invariant write offsets (granule-swizzled; f0&7 in {0,4} -> 8B align)
  int woff[2][2];  // [mt][nt]
#pragma unroll
  for (int mt = 0; mt < 2; ++mt)
#pragma unroll
    for (int nt = 0; nt < 2; ++nt) {
      int node = mg * 32 + mt * 16 + colL;
      int f0 = (2 * ng + nt) * 16 + q * 4;
      woff[mt][nt] =
          node * 128 + ((((f0 >> 3) ^ (node & 7)) << 3) | (f0 & 7));
    }

  __syncthreads();

  int ba = 0, bbv = 1, bc = 2;  // rotation indices (uniform)
  for (int step = 0; step < 64; ++step) {
    _Float16* p_n0rd[2] = {K3_R(0, ba), K3_R(1, ba)};
    _Float16* p_n0wr[2] = {K3_R(0, bbv), K3_R(1, bbv)};
    _Float16* p_n1rd[2] = {K3_R(0, bc), K3_R(1, bc)};
    _Float16* p_n1wr[2] = {K3_R(0, ba), K3_R(1, ba)};

    // ===== P0: n0 = tanh(W0 @ [A|h0] + b0), D[feat][node], both groups
    f32x4 acc[2][2][2];  // [g][mt][nt]
#pragma unroll
    for (int g = 0; g < 2; ++g)
#pragma unroll
      for (int mt = 0; mt < 2; ++mt)
#pragma unroll
        for (int nt = 0; nt < 2; ++nt) acc[g][mt][nt] = b0v[nt];
#pragma unroll
    for (int kc = 0; kc < 4; ++kc) {
      int gk = kc * 4 + q;
      f16x8 bh[2][2];
#pragma unroll
      for (int g = 0; g < 2; ++g)
#pragma unroll
        for (int mt = 0; mt < 2; ++mt) {
          int row = mg * 32 + mt * 16 + colL;
          bh[g][mt] =
              *(const f16x8*)&p_n0rd[g][row * 128 + ((gk ^ (row & 7)) << 3)];
        }
#pragma unroll
      for (int g = 0; g < 2; ++g)
#pragma unroll
        for (int mt = 0; mt < 2; ++mt)
#pragma unroll
          for (int nt = 0; nt < 2; ++nt)
            acc[g][mt][nt] = MFMAH(Wr[nt][2 + kc], bh[g][mt], acc[g][mt][nt]);
    }
    if (step > 0) {
      {
        int gk = q;
        f16x8 bh[2][2];
#pragma unroll
        for (int g = 0; g < 2; ++g)
#pragma unroll
          for (int mt = 0; mt < 2; ++mt) {
            int row = mg * 32 + mt * 16 + colL;
            bh[g][mt] =
                *(const f16x8*)&K3_A(g)[row * 64 + ((gk ^ (row & 7)) << 3)];
          }
#pragma unroll
        for (int g = 0; g < 2; ++g)
#pragma unroll
          for (int mt = 0; mt < 2; ++mt)
#pragma unroll
            for (int nt = 0; nt < 2; ++nt)
              acc[g][mt][nt] = MFMAH(Wr[nt][0], bh[g][mt], acc[g][mt][nt]);
      }
      if (step > 32) {
        int gk = 4 + q;
        f16x8 bh[2][2];
#pragma unroll
        for (int g = 0; g < 2; ++g)
#pragma unroll
          for (int mt = 0; mt < 2; ++mt) {
            int row = mg * 32 + mt * 16 + colL;
            bh[g][mt] =
                *(const f16x8*)&K3_A(g)[row * 64 + ((gk ^ (row & 7)) << 3)];
          }
#pragma unroll
        for (int g = 0; g < 2; ++g)
#pragma unroll
          for (int mt = 0; mt < 2; ++mt)
#pragma unroll
            for (int nt = 0; nt < 2; ++nt)
              acc[g][mt][nt] = MFMAH(Wr[nt][1], bh[g][mt], acc[g][mt][nt]);
      }
    }
#pragma unroll
    for (int g = 0; g < 2; ++g)
#pragma unroll
      for (int mt = 0; mt < 2; ++mt)
#pragma unroll
        for (int nt = 0; nt < 2; ++nt) {
          float t0 = fast_tanh(acc[g][mt][nt][0]);
          float t1 = fast_tanh(acc[g][mt][nt][1]);
          float t2 = fast_tanh(acc[g][mt][nt][2]);
          float t3 = fast_tanh(acc[g][mt][nt][3]);
          h2 lo = {(_Float16)t0, (_Float16)t1};
          h2 hi = {(_Float16)t2, (_Float16)t3};
          uint2 u = {__builtin_bit_cast(unsigned, lo),
                     __builtin_bit_cast(unsigned, hi)};
          *(uint2*)&p_n0wr[g][woff[mt][nt]] = u;
        }
    __syncthreads();  // bar A

    // ===== P1: n1 = tanh(W1 @ [n0|h1] + b1)
    f32x4 acc2[2][2][2];
#pragma unroll
    for (int g = 0; g < 2; ++g)
#pragma unroll
      for (int mt = 0; mt < 2; ++mt)
#pragma unroll
        for (int nt = 0; nt < 2; ++nt) acc2[g][mt][nt] = b1v[nt];
#pragma unroll
    for (int kc = 0; kc < 8; ++kc) {
      int gk = (kc & 3) * 4 + q;
      f16x8 bh[2][2];
#pragma unroll
      for (int g = 0; g < 2; ++g) {
        const _Float16* src = (kc < 4) ? p_n0wr[g] : p_n1rd[g];
#pragma unroll
        for (int mt = 0; mt < 2; ++mt) {
          int row = mg * 32 + mt * 16 + colL;
          bh[g][mt] = *(const f16x8*)&src[row * 128 + ((gk ^ (row & 7)) << 3)];
        }
      }
#pragma unroll
      for (int g = 0; g < 2; ++g)
#pragma unroll
        for (int mt = 0; mt < 2; ++mt)
#pragma unroll
          for (int nt = 0; nt < 2; ++nt)
            acc2[g][mt][nt] =
                MFMAH(Wr[nt][6 + kc], bh[g][mt], acc2[g][mt][nt]);
    }
    float paf[2][2];  // [g][mt] cls partial for node (colL-based)
#pragma unroll
    for (int g = 0; g < 2; ++g)
#pragma unroll
      for (int mt = 0; mt < 2; ++mt) paf[g][mt] = 0.f;
#pragma unroll
    for (int g = 0; g < 2; ++g)
#pragma unroll
      for (int mt = 0; mt < 2; ++mt)
#pragma unroll
        for (int nt = 0; nt < 2; ++nt) {
          float t0 = fast_tanh(acc2[g][mt][nt][0]);
          float t1 = fast_tanh(acc2[g][mt][nt][1]);
          float t2 = fast_tanh(acc2[g][mt][nt][2]);
          float t3 = fast_tanh(acc2[g][mt][nt][3]);
          h2 lo = {(_Float16)t0, (_Float16)t1};
          h2 hi = {(_Float16)t2, (_Float16)t3};
          paf[g][mt] = FDOT2(cw2[nt][0], lo, paf[g][mt]);
          paf[g][mt] = FDOT2(cw2[nt][1], hi, paf[g][mt]);
          uint2 u = {__builtin_bit_cast(unsigned, lo),
                     __builtin_bit_cast(unsigned, hi)};
          *(uint2*)&p_n1wr[g][woff[mt][nt]] = u;
        }
    // reduce cls partials over q (lanes +-16, +-32 share the node)
#pragma unroll
    for (int g = 0; g < 2; ++g)
#pragma unroll
      for (int mt = 0; mt < 2; ++mt) {
        float s = paf[g][mt];
        s += __shfl_xor(s, 16);
        s += __shfl_xor(s, 32);
        paf[g][mt] = s;
      }
    if (q == 0) {
#pragma unroll
      for (int g = 0; g < 2; ++g)
#pragma unroll
        for (int mt = 0; mt < 2; ++mt)
          K3_PS(g)[ng * 64 + mg * 32 + mt * 16 + colL] = paf[g][mt];
    }
    __syncthreads();  // bar B

    // ===== cls: all waves redundantly compute both groups' sigmoids.
    {
      float* ps0 = K3_PS(0);
      float* ps1 = K3_PS(1);
      float s0 = cbias + ps0[l] + ps0[64 + l] + ps0[128 + l] + ps0[192 + l];
      float s1 = cbias + ps1[l] + ps1[64 + l] + ps1[128 + l] + ps1[192 + l];
      float sg0 = fast_sigmoid(s0);
      float sg1 = fast_sigmoid(s1);
      int aidx = l * 64 + ((((step >> 3) ^ (l & 7)) << 3) | (step & 7));
      if (step < mval[0]) K3_A(0)[aidx] = (_Float16)sg0;
      if (step < mval[1]) K3_A(1)[aidx] = (_Float16)sg1;
    }
    int tmp = ba; ba = bbv; bbv = bc; bc = tmp;
  }
  __syncthreads();

  // ---- epilogue: write both groups' FULL 512x64 adj tiles, coalesced.
#pragma unroll
  for (int g = 0; g < 2; ++g) {
    const int qd = l & 15;
    const int rg4 = l >> 4;
    const int node0g = node0 + g * 64;
    const int ii0 = node0g & 511;
    const int badj = node0g >> 9;
    _Float16* Ag = K3_A(g);
    for (int rb = 0; rb < 64; rb += 4) {
      int r = w * 64 + rb + rg4;
      float4 v;
      float* vp = (float*)&v;
#pragma unroll
      for (int c = 0; c < 4; ++c) {
        int n = qd * 4 + c;
        int ii = ii0 + n;
        int base = (ii - 64 > 0) ? ii - 64 : 0;
        int mv = min(ii, 64);
        int k = r - base;
        float val = 0.f;
        if (k >= 0 && k < mv) val = (float)Ag[sw(n, k, 64)];
        vp[c] = val;
      }
      *(float4*)&adj[((size_t)badj * 512 + r) * 512 + ii0 + qd * 4] = v;
    }
  }
}

extern "C" void kernel_launch(void* const* d_in, const int* in_sizes, int n_in,
                              void* d_out, int out_size, void* d_ws,
                              size_t ws_size, hipStream_t stream) {
  const float* x = (const float*)d_in[0];
  const int* mask = (const int*)d_in[1];
  const float* gWih0 = (const float*)d_in[2];
  const float* gWhh0 = (const float*)d_in[3];
  const float* gbih0 = (const float*)d_in[4];
  const float* gbhh0 = (const float*)d_in[5];
  const float* gWih1 = (const float*)d_in[6];
  const float* gWhh1 = (const float*)d_in[7];
  const float* gbih1 = (const float*)d_in[8];
  const float* gbhh1 = (const float*)d_in[9];
  const float* eWih0 = (const float*)d_in[10];
  const float* eWhh0 = (const float*)d_in[11];
  const float* ebih0 = (const float*)d_in[12];
  const float* ebhh0 = (const float*)d_in[13];
  const float* eWih1 = (const float*)d_in[14];
  const float* eWhh1 = (const float*)d_in[15];
  const float* ebih1 = (const float*)d_in[16];
  const float* ebhh1 = (const float*)d_in[17];
  const float* clsW = (const float*)d_in[18];
  const float* clsb = (const float*)d_in[19];
  float* out = (float*)d_out;
  float* Y = out;
  float* adj = out + YSZ;
  float* P0 = adj;  // scratch overlay in adj region; k3 overwrites all of adj

  unsigned short* Wf = (unsigned short*)d_ws;
  hipLaunchKernelGGL(k0_prep, dim3(28), dim3(256), 0, stream, eWih0, eWhh0,
                     eWih1, eWhh1, Wf);
  hipLaunchKernelGGL(k1_gemm, dim3(256), dim3(256), 0, stream, x, gWih0,
                     gbih0, gbhh0, P0);
  hipLaunchKernelGGL(k2_v9, dim3(4), dim3(512), 0, stream, P0, gWhh0, gWih1,
                     gWhh1, gbih1, gbhh1, mask, Y);
  hipFuncSetAttribute(reinterpret_cast<const void*>(k3_edge_f16),
                      hipFuncAttributeMaxDynamicSharedMemorySize, LDSTOT);
  hipLaunchKernelGGL(k3_edge_f16, dim3(256), dim3(512), LDSTOT, stream, Y,
                     Wf, ebih0, ebhh0, ebih1, ebhh1, clsW, clsb, adj);
}